// Round 1
// baseline (837.345 us; speedup 1.0000x reference)
//
#include <hip/hip_runtime.h>
#include <cstdint>
#include <cstddef>

// Problem constants
#define TB 4
#define TT 2048
#define TC 1024
#define NH 16
#define HD 64
#define MROWS (TB * TT)   // 8192

typedef __bf16 bf16;
typedef unsigned short u16;
typedef __bf16 bf16x8 __attribute__((ext_vector_type(8)));
typedef float floatx4 __attribute__((ext_vector_type(4)));
typedef unsigned short ushort8 __attribute__((ext_vector_type(8)));
typedef unsigned short ushort4v __attribute__((ext_vector_type(4)));

static __device__ __forceinline__ u16 f2bfbits(float f) {
    bf16 b = (bf16)f;
    return __builtin_bit_cast(u16, b);
}

// ---------------------------------------------------------------------------
// f32 -> bf16 cast (vectorized x4)
__global__ void cast_bf16_kernel(const float* __restrict__ in, u16* __restrict__ out, int n4) {
    int i = blockIdx.x * blockDim.x + threadIdx.x;
    if (i < n4) {
        float4 v = reinterpret_cast<const float4*>(in)[i];
        ushort4v o;
        o.x = f2bfbits(v.x); o.y = f2bfbits(v.y); o.z = f2bfbits(v.z); o.w = f2bfbits(v.w);
        reinterpret_cast<ushort4v*>(out)[i] = o;
    }
}

// ---------------------------------------------------------------------------
// [K][N] f32 -> [N][K] bf16 transpose-cast. grid (N/32, K/32), block (32,8)
__global__ void transpose_cast_kernel(const float* __restrict__ in, u16* __restrict__ out,
                                      int K, int N) {
    __shared__ float tile[32][33];
    const int n0 = blockIdx.x * 32, k0 = blockIdx.y * 32;
    const int tx = threadIdx.x, ty = threadIdx.y;
    for (int r = 0; r < 32; r += 8)
        tile[ty + r][tx] = in[(size_t)(k0 + ty + r) * N + n0 + tx];
    __syncthreads();
    for (int r = 0; r < 32; r += 8)
        out[(size_t)(n0 + ty + r) * K + k0 + tx] = f2bfbits(tile[tx][ty + r]);
}

// ---------------------------------------------------------------------------
// GEMM: C[M][N] = A[M][K] @ Bt[N][K]^T + bias, optional exact GELU.
// 128x128 tile, BK=32, 4 waves (2x2), each wave 64x64 via 4x4 mfma 16x16x32.
// LDS stride 40 (pad 32->40: 2-way bank aliasing only, which is free).
#define LDA 40
template <int GELU>
__global__ __launch_bounds__(256) void gemm_bt_kernel(
    const u16* __restrict__ A, const u16* __restrict__ Bt,
    const float* __restrict__ bias, u16* __restrict__ Cmat,
    int Msz, int Nsz, int Ksz)
{
    __shared__ u16 As[128 * LDA];
    __shared__ u16 Bs[128 * LDA];
    const int tid  = threadIdx.x;
    const int wave = tid >> 6, lane = tid & 63;
    const int quad = lane >> 4, l16 = lane & 15;
    const int wm = (wave >> 1) * 64, wn = (wave & 1) * 64;
    const int m0 = blockIdx.y * 128, n0 = blockIdx.x * 128;

    // staging: 512 16B-chunks per matrix, 2 per thread
    const int c0 = tid, c1 = tid + 256;
    const int ar0 = c0 >> 2, aj0 = (c0 & 3) * 8;
    const int ar1 = c1 >> 2, aj1 = (c1 & 3) * 8;

    floatx4 acc[4][4];
    for (int i = 0; i < 4; i++)
        for (int j = 0; j < 4; j++)
            acc[i][j] = (floatx4){0.f, 0.f, 0.f, 0.f};

    for (int k0 = 0; k0 < Ksz; k0 += 32) {
        ushort8 a0 = *reinterpret_cast<const ushort8*>(A  + (size_t)(m0 + ar0) * Ksz + k0 + aj0);
        ushort8 a1 = *reinterpret_cast<const ushort8*>(A  + (size_t)(m0 + ar1) * Ksz + k0 + aj1);
        ushort8 b0 = *reinterpret_cast<const ushort8*>(Bt + (size_t)(n0 + ar0) * Ksz + k0 + aj0);
        ushort8 b1 = *reinterpret_cast<const ushort8*>(Bt + (size_t)(n0 + ar1) * Ksz + k0 + aj1);
        __syncthreads();
        *reinterpret_cast<ushort8*>(As + ar0 * LDA + aj0) = a0;
        *reinterpret_cast<ushort8*>(As + ar1 * LDA + aj1) = a1;
        *reinterpret_cast<ushort8*>(Bs + ar0 * LDA + aj0) = b0;
        *reinterpret_cast<ushort8*>(Bs + ar1 * LDA + aj1) = b1;
        __syncthreads();
        bf16x8 af[4], bfr[4];
        for (int i = 0; i < 4; i++)
            af[i] = *reinterpret_cast<const bf16x8*>(As + (wm + i * 16 + l16) * LDA + quad * 8);
        for (int j = 0; j < 4; j++)
            bfr[j] = *reinterpret_cast<const bf16x8*>(Bs + (wn + j * 16 + l16) * LDA + quad * 8);
        for (int i = 0; i < 4; i++)
            for (int j = 0; j < 4; j++)
                acc[i][j] = __builtin_amdgcn_mfma_f32_16x16x32_bf16(af[i], bfr[j], acc[i][j], 0, 0, 0);
    }

    // epilogue: C layout col=lane&15, row=quad*4+reg (m89-verified)
    for (int i = 0; i < 4; i++) {
        const int row_base = m0 + wm + i * 16 + quad * 4;
        for (int j = 0; j < 4; j++) {
            const int col = n0 + wn + j * 16 + l16;
            const float bv = bias[col];
            for (int r = 0; r < 4; r++) {
                float v = acc[i][j][r] + bv;
                if (GELU) v = 0.5f * v * (1.0f + erff(v * 0.70710678118f));
                Cmat[(size_t)(row_base + r) * Nsz + col] = f2bfbits(v);
            }
        }
    }
}

// ---------------------------------------------------------------------------
// Flash attention, causal. Block = (64 q-rows) x (b,h); 4 waves x 16 q-rows.
// k-tiles of 32. qkv: [B*T][3C] bf16; y: [B*T][C] bf16.
__global__ __launch_bounds__(256) void attn_kernel(const u16* __restrict__ qkv,
                                                   u16* __restrict__ y)
{
    __shared__ u16 Vt[HD * 40];        // V-tile transposed: [d=64][k=32], stride 40
    __shared__ u16 Pw[4 * 16 * 40];    // per-wave P: [16 q][32 k], stride 40
    const int tid  = threadIdx.x;
    const int wave = tid >> 6, lane = tid & 63;
    const int quad = lane >> 4, l16 = lane & 15;
    const int qt = blockIdx.x, h = blockIdx.y, b = blockIdx.z;
    const int q0b = qt * 64;
    const int q0w = q0b + wave * 16;
    const int rowbase = b * TT;
    const int S3C = 3 * TC;

    // Q fragments (A-operand: m=lane&15, k=quad*8+j), pre-scaled by 1/8 (exact in bf16)
    bf16x8 qf0, qf1;
    {
        const u16* qrow = qkv + (size_t)(rowbase + q0w + l16) * S3C + h * HD + quad * 8;
        bf16x8 t0 = *reinterpret_cast<const bf16x8*>(qrow);
        bf16x8 t1 = *reinterpret_cast<const bf16x8*>(qrow + 32);
        for (int i = 0; i < 8; i++) {
            t0[i] = (bf16)((float)t0[i] * 0.125f);
            t1[i] = (bf16)((float)t1[i] * 0.125f);
        }
        qf0 = t0; qf1 = t1;
    }

    float m_r[4], l_r[4];
    floatx4 o_acc[4];
    for (int r = 0; r < 4; r++) { m_r[r] = -__builtin_inff(); l_r[r] = 0.f; }
    for (int n = 0; n < 4; n++) o_acc[n] = (floatx4){0.f, 0.f, 0.f, 0.f};

    const int kend = q0b + 64;
    for (int k0 = 0; k0 < kend; k0 += 32) {
        // cooperative stage of V[k0..k0+31][64] transposed into Vt
        {
            const int vr = tid >> 3;
            const int dc = (tid & 7) * 8;
            ushort8 vv = *reinterpret_cast<const ushort8*>(
                qkv + (size_t)(rowbase + k0 + vr) * S3C + 2 * TC + h * HD + dc);
            __syncthreads();   // previous iter's reads of Vt are done
            for (int j = 0; j < 8; j++) Vt[(dc + j) * 40 + vr] = vv[j];
            __syncthreads();
        }
        if (k0 <= q0w + 15) {   // wave not fully masked
            // K fragments (B-operand: n=lane&15 -> k-col, k=quad*8+j -> d), direct from global
            const u16* krow = qkv + (size_t)(rowbase + k0 + l16) * S3C + TC + h * HD + quad * 8;
            bf16x8 kf0a = *reinterpret_cast<const bf16x8*>(krow);
            bf16x8 kf0b = *reinterpret_cast<const bf16x8*>(krow + 32);
            bf16x8 kf1a = *reinterpret_cast<const bf16x8*>(krow + 16 * S3C);
            bf16x8 kf1b = *reinterpret_cast<const bf16x8*>(krow + 16 * S3C + 32);
            floatx4 s0 = {0.f, 0.f, 0.f, 0.f}, s1 = {0.f, 0.f, 0.f, 0.f};
            s0 = __builtin_amdgcn_mfma_f32_16x16x32_bf16(qf0, kf0a, s0, 0, 0, 0);
            s0 = __builtin_amdgcn_mfma_f32_16x16x32_bf16(qf1, kf0b, s0, 0, 0, 0);
            s1 = __builtin_amdgcn_mfma_f32_16x16x32_bf16(qf0, kf1a, s1, 0, 0, 0);
            s1 = __builtin_amdgcn_mfma_f32_16x16x32_bf16(qf1, kf1b, s1, 0, 0, 0);

            u16* prow = Pw + wave * (16 * 40);
            for (int r = 0; r < 4; r++) {
                const int qr = q0w + quad * 4 + r;
                float v0 = (k0 + l16 > qr)      ? -__builtin_inff() : s0[r];
                float v1 = (k0 + 16 + l16 > qr) ? -__builtin_inff() : s1[r];
                float mx = fmaxf(v0, v1);
                for (int off = 1; off < 16; off <<= 1) mx = fmaxf(mx, __shfl_xor(mx, off, 16));
                const float mnew  = fmaxf(m_r[r], mx);
                const float alpha = __expf(m_r[r] - mnew);
                const float p0 = __expf(v0 - mnew);
                const float p1 = __expf(v1 - mnew);
                float rs = p0 + p1;
                for (int off = 1; off < 16; off <<= 1) rs += __shfl_xor(rs, off, 16);
                l_r[r] = l_r[r] * alpha + rs;
                m_r[r] = mnew;
                for (int n = 0; n < 4; n++) o_acc[n][r] *= alpha;
                prow[(quad * 4 + r) * 40 + l16]      = f2bfbits(p0);
                prow[(quad * 4 + r) * 40 + 16 + l16] = f2bfbits(p1);
            }
            // P as A-operand; V as B-operand from Vt
            bf16x8 pf = *reinterpret_cast<const bf16x8*>(prow + l16 * 40 + quad * 8);
            for (int n = 0; n < 4; n++) {
                bf16x8 vf = *reinterpret_cast<const bf16x8*>(Vt + (n * 16 + l16) * 40 + quad * 8);
                o_acc[n] = __builtin_amdgcn_mfma_f32_16x16x32_bf16(pf, vf, o_acc[n], 0, 0, 0);
            }
        }
    }

    for (int r = 0; r < 4; r++) l_r[r] = 1.0f / l_r[r];
    for (int n = 0; n < 4; n++)
        for (int r = 0; r < 4; r++) {
            const int row = rowbase + q0w + quad * 4 + r;
            y[(size_t)row * TC + h * HD + n * 16 + l16] = f2bfbits(o_acc[n][r] * l_r[r]);
        }
}

// ---------------------------------------------------------------------------
// LayerNorm(a + b) * g + beta. One block per row, 256 threads, C=1024.
template <typename AT, typename OT>
__global__ __launch_bounds__(256) void ln_kernel(
    const AT* __restrict__ a, const bf16* __restrict__ bres,
    const float* __restrict__ g, const float* __restrict__ be,
    OT* __restrict__ out)
{
    const int row = blockIdx.x;
    const int tid = threadIdx.x;
    const size_t base = (size_t)row * TC;
    float v[4];
    for (int i = 0; i < 4; i++) {
        const int c = tid + i * 256;
        v[i] = (float)a[base + c] + (float)bres[base + c];
    }
    float s  = v[0] + v[1] + v[2] + v[3];
    float sq = v[0]*v[0] + v[1]*v[1] + v[2]*v[2] + v[3]*v[3];
    for (int off = 32; off >= 1; off >>= 1) {
        s  += __shfl_xor(s, off, 64);
        sq += __shfl_xor(sq, off, 64);
    }
    __shared__ float red[8];
    const int wv = tid >> 6, lane = tid & 63;
    if (lane == 0) { red[wv] = s; red[4 + wv] = sq; }
    __syncthreads();
    s  = red[0] + red[1] + red[2] + red[3];
    sq = red[4] + red[5] + red[6] + red[7];
    const float mu   = s * (1.0f / TC);
    const float var  = sq * (1.0f / TC) - mu * mu;
    const float rsig = rsqrtf(var + 1e-5f);
    for (int i = 0; i < 4; i++) {
        const int c = tid + i * 256;
        out[base + c] = (OT)((v[i] - mu) * rsig * g[c] + be[c]);
    }
}

// ---------------------------------------------------------------------------
extern "C" void kernel_launch(void* const* d_in, const int* in_sizes, int n_in,
                              void* d_out, int out_size, void* d_ws, size_t ws_size,
                              hipStream_t stream)
{
    const float* x     = (const float*)d_in[0];
    const float* w_qkv = (const float*)d_in[1];
    const float* b_qkv = (const float*)d_in[2];
    const float* ln1_g = (const float*)d_in[3];
    const float* ln1_b = (const float*)d_in[4];
    const float* w_fc1 = (const float*)d_in[5];
    const float* b_fc1 = (const float*)d_in[6];
    const float* w_fc2 = (const float*)d_in[7];
    const float* b_fc2 = (const float*)d_in[8];
    const float* ln2_g = (const float*)d_in[9];
    const float* ln2_b = (const float*)d_in[10];
    float* out = (float*)d_out;

    char* ws = (char*)d_ws;
    const size_t MB = 1ull << 20;
    // workspace layout (total 182 MB; mlp reuses the qkv region)
    u16* xb    = (u16*)(ws + 0);        // [8192][1024]  16 MB
    u16* wqkvT = (u16*)(ws + 16 * MB);  // [3072][1024]   6 MB
    u16* wfc1T = (u16*)(ws + 22 * MB);  // [4096][1024]   8 MB
    u16* wfc2T = (u16*)(ws + 30 * MB);  // [1024][4096]   8 MB
    u16* qkv   = (u16*)(ws + 38 * MB);  // [8192][3072]  48 MB
    u16* yb    = (u16*)(ws + 86 * MB);  // [8192][1024]  16 MB
    u16* x1    = (u16*)(ws + 102 * MB); // [8192][1024]  16 MB
    u16* hb    = (u16*)(ws + 118 * MB); // [8192][4096]  64 MB
    u16* mlp   = (u16*)(ws + 38 * MB);  // reuse qkv region (dead after attention)

    // prep: casts + weight transposes
    cast_bf16_kernel<<<(MROWS * TC / 4 + 255) / 256, 256, 0, stream>>>(x, xb, MROWS * TC / 4);
    transpose_cast_kernel<<<dim3(3 * TC / 32, TC / 32), dim3(32, 8), 0, stream>>>(w_qkv, wqkvT, TC, 3 * TC);
    transpose_cast_kernel<<<dim3(4 * TC / 32, TC / 32), dim3(32, 8), 0, stream>>>(w_fc1, wfc1T, TC, 4 * TC);
    transpose_cast_kernel<<<dim3(TC / 32, 4 * TC / 32), dim3(32, 8), 0, stream>>>(w_fc2, wfc2T, 4 * TC, TC);

    // qkv = x @ w_qkv + b_qkv
    gemm_bt_kernel<0><<<dim3(3 * TC / 128, MROWS / 128), 256, 0, stream>>>(
        xb, wqkvT, b_qkv, qkv, MROWS, 3 * TC, TC);
    // y = attention(qkv)
    attn_kernel<<<dim3(TT / 64, NH, TB), 256, 0, stream>>>(qkv, yb);
    // x1 = LN1(x + y)
    ln_kernel<float, bf16><<<MROWS, 256, 0, stream>>>(x, (const bf16*)yb, ln1_g, ln1_b, (bf16*)x1);
    // h = gelu(x1 @ w_fc1 + b_fc1)
    gemm_bt_kernel<1><<<dim3(4 * TC / 128, MROWS / 128), 256, 0, stream>>>(
        (const u16*)x1, wfc1T, b_fc1, hb, MROWS, 4 * TC, TC);
    // mlp = h @ w_fc2 + b_fc2
    gemm_bt_kernel<0><<<dim3(TC / 128, MROWS / 128), 256, 0, stream>>>(
        hb, wfc2T, b_fc2, mlp, MROWS, TC, 4 * TC);
    // out = LN2(x1 + mlp)
    ln_kernel<bf16, float><<<MROWS, 256, 0, stream>>>(
        (const bf16*)x1, (const bf16*)mlp, ln2_g, ln2_b, out);
}

// Round 2
// 597.958 us; speedup vs baseline: 1.4003x; 1.4003x over previous
//
#include <hip/hip_runtime.h>
#include <cstdint>
#include <cstddef>

// Problem constants
#define TB 4
#define TT 2048
#define TC 1024
#define NH 16
#define HD 64
#define MROWS (TB * TT)   // 8192

typedef __bf16 bf16;
typedef unsigned short u16;
typedef __bf16 bf16x8 __attribute__((ext_vector_type(8)));
typedef float floatx4 __attribute__((ext_vector_type(4)));
typedef unsigned short ushort8 __attribute__((ext_vector_type(8)));
typedef unsigned short ushort4v __attribute__((ext_vector_type(4)));

static __device__ __forceinline__ u16 f2bfbits(float f) {
    bf16 b = (bf16)f;
    return __builtin_bit_cast(u16, b);
}

// async global->LDS 16B: addrspace pointers built via integer casts
// (generic LDS pointer low 32 bits == AS(3) offset on gfx9 aperture layout)
static __device__ __forceinline__ void gld_lds16(const u16* g, const u16* lds) {
    __builtin_amdgcn_global_load_lds(
        (const __attribute__((address_space(1))) unsigned int*)(uintptr_t)g,
        (__attribute__((address_space(3))) unsigned int*)(unsigned int)(uintptr_t)lds,
        16, 0, 0);
}

// ---------------------------------------------------------------------------
// f32 -> bf16 cast (vectorized x4)
__global__ void cast_bf16_kernel(const float* __restrict__ in, u16* __restrict__ out, int n4) {
    int i = blockIdx.x * blockDim.x + threadIdx.x;
    if (i < n4) {
        float4 v = reinterpret_cast<const float4*>(in)[i];
        ushort4v o;
        o.x = f2bfbits(v.x); o.y = f2bfbits(v.y); o.z = f2bfbits(v.z); o.w = f2bfbits(v.w);
        reinterpret_cast<ushort4v*>(out)[i] = o;
    }
}

// ---------------------------------------------------------------------------
// [K][N] f32 -> [N][K] bf16 transpose-cast. grid (N/32, K/32), block (32,8)
__global__ void transpose_cast_kernel(const float* __restrict__ in, u16* __restrict__ out,
                                      int K, int N) {
    __shared__ float tile[32][33];
    const int n0 = blockIdx.x * 32, k0 = blockIdx.y * 32;
    const int tx = threadIdx.x, ty = threadIdx.y;
    for (int r = 0; r < 32; r += 8)
        tile[ty + r][tx] = in[(size_t)(k0 + ty + r) * N + n0 + tx];
    __syncthreads();
    for (int r = 0; r < 32; r += 8)
        out[(size_t)(n0 + ty + r) * K + k0 + tx] = f2bfbits(tile[tx][ty + r]);
}

// ---------------------------------------------------------------------------
// GEMM (m97 structure): C[M][N] = A[M][K] @ Bt[N][K]^T + bias, optional GELU.
// 128x128 tile, BK=32, 4 waves, global_load_lds width-16 staging, unpadded
// 32-elem LDS rows (16B-aligned b128 frag reads).
template <int GELU>
__global__ __launch_bounds__(256) void gemm_bt_kernel(
    const u16* __restrict__ A, const u16* __restrict__ Bt,
    const float* __restrict__ bias, u16* __restrict__ Cmat,
    int Msz, int Nsz, int Ksz)
{
    __shared__ u16 As[128 * 32];
    __shared__ u16 Bs[128 * 32];
    const int tid  = threadIdx.x;
    const int wave = tid >> 6, lane = tid & 63;
    const int quad = lane >> 4, l16 = lane & 15;
    const int wm = (wave >> 1) * 64, wn = (wave & 1) * 64;
    const int m0 = blockIdx.y * 128, n0 = blockIdx.x * 128;

    floatx4 acc[4][4];
    for (int i = 0; i < 4; i++)
        for (int j = 0; j < 4; j++)
            acc[i][j] = (floatx4){0.f, 0.f, 0.f, 0.f};

    for (int k0 = 0; k0 < Ksz; k0 += 32) {
        __syncthreads();   // prior-iter LDS reads complete before overwrite
#pragma unroll
        for (int i = 0; i < 2; i++) {
            const int c   = wave * 128 + i * 64 + lane;       // 16B chunk index
            const int row = c >> 2, col = (c & 3) * 8;
            const u16* ldst = As + (wave * 128 + i * 64) * 8; // wave-uniform base
            gld_lds16(A  + (size_t)(m0 + row) * Ksz + k0 + col, ldst);
            gld_lds16(Bt + (size_t)(n0 + row) * Ksz + k0 + col, Bs + (wave * 128 + i * 64) * 8);
        }
        __syncthreads();   // drains vmcnt -> LDS populated

        bf16x8 af[4], bfr[4];
        for (int i = 0; i < 4; i++)
            af[i] = *reinterpret_cast<const bf16x8*>(As + (wm + i * 16 + l16) * 32 + quad * 8);
        for (int j = 0; j < 4; j++)
            bfr[j] = *reinterpret_cast<const bf16x8*>(Bs + (wn + j * 16 + l16) * 32 + quad * 8);
        for (int i = 0; i < 4; i++)
            for (int j = 0; j < 4; j++)
                acc[i][j] = __builtin_amdgcn_mfma_f32_16x16x32_bf16(af[i], bfr[j], acc[i][j], 0, 0, 0);
    }

    // epilogue: C layout col=lane&15, row=quad*4+reg
    for (int i = 0; i < 4; i++) {
        const int row_base = m0 + wm + i * 16 + quad * 4;
        for (int j = 0; j < 4; j++) {
            const int col = n0 + wn + j * 16 + l16;
            const float bv = bias[col];
            for (int r = 0; r < 4; r++) {
                float v = acc[i][j][r] + bv;
                if (GELU) v = 0.5f * v * (1.0f + erff(v * 0.70710678118f));
                Cmat[(size_t)(row_base + r) * Nsz + col] = f2bfbits(v);
            }
        }
    }
}

// ---------------------------------------------------------------------------
// Flash attention, causal, S^T formulation.
// Block: 256 thr (4 waves x 16 q), processes q-tiles {bx, 31-bx} sequentially
// (uniform 66 k-iterations/block). K,V staged cooperatively in double-buffered
// LDS, 1 barrier/iter, staging globals prefetched into regs across barrier.
#define LDK 64
#define LDV 40
#define LP  32
__global__ __launch_bounds__(256) void attn_kernel(const u16* __restrict__ qkv,
                                                   u16* __restrict__ y)
{
    __shared__ u16 Ks[2 * 32 * LDK];   // [buf][key 0..31][d 0..63]
    __shared__ u16 Vt[2 * 64 * LDV];   // [buf][d 0..63][k 0..31]
    __shared__ u16 Pw[4 * 16 * LP];    // per-wave P^T staging [q 0..15][k 0..31]
    const int tid  = threadIdx.x;
    const int wave = tid >> 6, lane = tid & 63;
    const int quad = lane >> 4, l16 = lane & 15;
    const int h = blockIdx.y, b = blockIdx.z;
    const int rowbase = b * TT;
    const int S3C = 3 * TC;

    // staging roles (fixed per thread)
    const int vrp = tid >> 3;            // tid<128: V row-pair 0..15
    const int vdc = (tid & 7) * 8;       // V d-chunk
    const int ku  = tid - 128;           // tid>=128: K task 0..127
    const int krow = ku >> 2, kcc = (ku & 3) * 16;

    for (int pass = 0; pass < 2; pass++) {
        const int qt  = pass ? (31 - (int)blockIdx.x) : (int)blockIdx.x;
        const int q0b = qt * 64;
        const int q0w = q0b + wave * 16;
        const int kend = q0b + 64;

        __syncthreads();   // protect LDS from previous pass's reads

        // Q as B-operand frags: B[n=q=l16][d=quad*8+j], pre-scaled by 1/8
        bf16x8 qf0, qf1;
        {
            const u16* qrow = qkv + (size_t)(rowbase + q0w + l16) * S3C + h * HD + quad * 8;
            bf16x8 t0 = *reinterpret_cast<const bf16x8*>(qrow);
            bf16x8 t1 = *reinterpret_cast<const bf16x8*>(qrow + 32);
            for (int i = 0; i < 8; i++) {
                t0[i] = (bf16)((float)t0[i] * 0.125f);
                t1[i] = (bf16)((float)t1[i] * 0.125f);
            }
            qf0 = t0; qf1 = t1;
        }

        float m_s = -__builtin_inff(), l_s = 0.f;
        floatx4 o_acc[4];
        for (int n = 0; n < 4; n++) o_acc[n] = (floatx4){0.f, 0.f, 0.f, 0.f};

        // prefetch tile 0 staging into regs
        ushort8 r0, r1;
        {
            if (tid < 128) {
                const u16* vb = qkv + (size_t)(rowbase + 2 * vrp) * S3C + 2 * TC + h * HD + vdc;
                r0 = *reinterpret_cast<const ushort8*>(vb);
                r1 = *reinterpret_cast<const ushort8*>(vb + S3C);
            } else {
                const u16* kb = qkv + (size_t)(rowbase + krow) * S3C + TC + h * HD + kcc;
                r0 = *reinterpret_cast<const ushort8*>(kb);
                r1 = *reinterpret_cast<const ushort8*>(kb + 8);
            }
        }

        int buf = 0;
        for (int k0 = 0; k0 < kend; k0 += 32) {
            // write staged regs into LDS[buf]
            if (tid < 128) {
                u16* vb = Vt + buf * (64 * LDV);
                for (int j = 0; j < 8; j++) {
                    unsigned int pk = (unsigned int)r0[j] | ((unsigned int)r1[j] << 16);
                    *reinterpret_cast<unsigned int*>(vb + (vdc + j) * LDV + 2 * vrp) = pk;
                }
            } else {
                u16* kb = Ks + buf * (32 * LDK) + krow * LDK + kcc;
                *reinterpret_cast<ushort8*>(kb)     = r0;
                *reinterpret_cast<ushort8*>(kb + 8) = r1;
            }
            __syncthreads();

            // prefetch next tile
            if (k0 + 32 < kend) {
                const int kn = k0 + 32;
                if (tid < 128) {
                    const u16* vb = qkv + (size_t)(rowbase + kn + 2 * vrp) * S3C + 2 * TC + h * HD + vdc;
                    r0 = *reinterpret_cast<const ushort8*>(vb);
                    r1 = *reinterpret_cast<const ushort8*>(vb + S3C);
                } else {
                    const u16* kb = qkv + (size_t)(rowbase + kn + krow) * S3C + TC + h * HD + kcc;
                    r0 = *reinterpret_cast<const ushort8*>(kb);
                    r1 = *reinterpret_cast<const ushort8*>(kb + 8);
                }
            }

            if (k0 <= q0w + 15) {   // wave not fully masked
                const u16* ksb = Ks + buf * (32 * LDK);
                // S^T = K·Q^T: two 16-key subtiles
                floatx4 st[2];
                for (int t = 0; t < 2; t++) {
                    bf16x8 ka = *reinterpret_cast<const bf16x8*>(ksb + (t * 16 + l16) * LDK + quad * 8);
                    bf16x8 kbf = *reinterpret_cast<const bf16x8*>(ksb + (t * 16 + l16) * LDK + 32 + quad * 8);
                    floatx4 s = {0.f, 0.f, 0.f, 0.f};
                    s = __builtin_amdgcn_mfma_f32_16x16x32_bf16(ka, qf0, s, 0, 0, 0);
                    s = __builtin_amdgcn_mfma_f32_16x16x32_bf16(kbf, qf1, s, 0, 0, 0);
                    st[t] = s;
                }
                // softmax over k (per lane: q = q0w + l16, 8 k-values)
                const int q = q0w + l16;
                float v[8];
                for (int t = 0; t < 2; t++)
                    for (int r = 0; r < 4; r++) {
                        const int key = k0 + t * 16 + quad * 4 + r;
                        v[t * 4 + r] = (key > q) ? -__builtin_inff() : st[t][r];
                    }
                float mx = v[0];
                for (int i = 1; i < 8; i++) mx = fmaxf(mx, v[i]);
                mx = fmaxf(mx, __shfl_xor(mx, 16));
                mx = fmaxf(mx, __shfl_xor(mx, 32));
                const float mnew  = fmaxf(m_s, mx);
                const float alpha = __expf(m_s - mnew);
                float p[8], rs = 0.f;
                for (int i = 0; i < 8; i++) { p[i] = __expf(v[i] - mnew); rs += p[i]; }
                rs += __shfl_xor(rs, 16);
                rs += __shfl_xor(rs, 32);
                l_s = l_s * alpha + rs;
                m_s = mnew;
                for (int n = 0; n < 4; n++) o_acc[n] *= alpha;

                // pack P^T into per-wave LDS: Pw[q=l16][k = t*16 + quad*4 + r]
                u16* pwb = Pw + wave * (16 * LP);
                for (int t = 0; t < 2; t++) {
                    ushort4v pk;
                    pk.x = f2bfbits(p[t * 4 + 0]); pk.y = f2bfbits(p[t * 4 + 1]);
                    pk.z = f2bfbits(p[t * 4 + 2]); pk.w = f2bfbits(p[t * 4 + 3]);
                    *reinterpret_cast<ushort4v*>(pwb + l16 * LP + t * 16 + quad * 4) = pk;
                }
                // PV: O^T += V^T · P^T (A = V^T frag, B = P frag), K=32
                bf16x8 pf = *reinterpret_cast<const bf16x8*>(pwb + l16 * LP + quad * 8);
                const u16* vtb = Vt + buf * (64 * LDV);
                for (int n = 0; n < 4; n++) {
                    bf16x8 vf = *reinterpret_cast<const bf16x8*>(vtb + (n * 16 + l16) * LDV + quad * 8);
                    o_acc[n] = __builtin_amdgcn_mfma_f32_16x16x32_bf16(vf, pf, o_acc[n], 0, 0, 0);
                }
            }
            buf ^= 1;
        }

        // write out: O^T C-layout: col=l16=q, row=quad*4+r=d_local
        const float li = 1.0f / l_s;
        u16* yrow = y + (size_t)(rowbase + q0w + l16) * TC + h * HD;
        for (int n = 0; n < 4; n++) {
            ushort4v ov;
            ov.x = f2bfbits(o_acc[n][0] * li);
            ov.y = f2bfbits(o_acc[n][1] * li);
            ov.z = f2bfbits(o_acc[n][2] * li);
            ov.w = f2bfbits(o_acc[n][3] * li);
            *reinterpret_cast<ushort4v*>(yrow + n * 16 + quad * 4) = ov;
        }
    }
}

// ---------------------------------------------------------------------------
// LayerNorm(a + b) * g + beta. One block per row, 256 threads, C=1024.
template <typename AT, typename OT>
__global__ __launch_bounds__(256) void ln_kernel(
    const AT* __restrict__ a, const bf16* __restrict__ bres,
    const float* __restrict__ g, const float* __restrict__ be,
    OT* __restrict__ out)
{
    const int row = blockIdx.x;
    const int tid = threadIdx.x;
    const size_t base = (size_t)row * TC;
    float v[4];
    for (int i = 0; i < 4; i++) {
        const int c = tid + i * 256;
        v[i] = (float)a[base + c] + (float)bres[base + c];
    }
    float s  = v[0] + v[1] + v[2] + v[3];
    float sq = v[0]*v[0] + v[1]*v[1] + v[2]*v[2] + v[3]*v[3];
    for (int off = 32; off >= 1; off >>= 1) {
        s  += __shfl_xor(s, off, 64);
        sq += __shfl_xor(sq, off, 64);
    }
    __shared__ float red[8];
    const int wv = tid >> 6, lane = tid & 63;
    if (lane == 0) { red[wv] = s; red[4 + wv] = sq; }
    __syncthreads();
    s  = red[0] + red[1] + red[2] + red[3];
    sq = red[4] + red[5] + red[6] + red[7];
    const float mu   = s * (1.0f / TC);
    const float var  = sq * (1.0f / TC) - mu * mu;
    const float rsig = rsqrtf(var + 1e-5f);
    for (int i = 0; i < 4; i++) {
        const int c = tid + i * 256;
        out[base + c] = (OT)((v[i] - mu) * rsig * g[c] + be[c]);
    }
}

// ---------------------------------------------------------------------------
extern "C" void kernel_launch(void* const* d_in, const int* in_sizes, int n_in,
                              void* d_out, int out_size, void* d_ws, size_t ws_size,
                              hipStream_t stream)
{
    const float* x     = (const float*)d_in[0];
    const float* w_qkv = (const float*)d_in[1];
    const float* b_qkv = (const float*)d_in[2];
    const float* ln1_g = (const float*)d_in[3];
    const float* ln1_b = (const float*)d_in[4];
    const float* w_fc1 = (const float*)d_in[5];
    const float* b_fc1 = (const float*)d_in[6];
    const float* w_fc2 = (const float*)d_in[7];
    const float* b_fc2 = (const float*)d_in[8];
    const float* ln2_g = (const float*)d_in[9];
    const float* ln2_b = (const float*)d_in[10];
    float* out = (float*)d_out;

    char* ws = (char*)d_ws;
    const size_t MB = 1ull << 20;
    u16* xb    = (u16*)(ws + 0);        // [8192][1024]  16 MB
    u16* wqkvT = (u16*)(ws + 16 * MB);  // [3072][1024]   6 MB
    u16* wfc1T = (u16*)(ws + 22 * MB);  // [4096][1024]   8 MB
    u16* wfc2T = (u16*)(ws + 30 * MB);  // [1024][4096]   8 MB
    u16* qkv   = (u16*)(ws + 38 * MB);  // [8192][3072]  48 MB
    u16* yb    = (u16*)(ws + 86 * MB);  // [8192][1024]  16 MB
    u16* x1    = (u16*)(ws + 102 * MB); // [8192][1024]  16 MB
    u16* hb    = (u16*)(ws + 118 * MB); // [8192][4096]  64 MB
    u16* mlp   = (u16*)(ws + 38 * MB);  // reuse qkv region (dead after attention)

    cast_bf16_kernel<<<(MROWS * TC / 4 + 255) / 256, 256, 0, stream>>>(x, xb, MROWS * TC / 4);
    transpose_cast_kernel<<<dim3(3 * TC / 32, TC / 32), dim3(32, 8), 0, stream>>>(w_qkv, wqkvT, TC, 3 * TC);
    transpose_cast_kernel<<<dim3(4 * TC / 32, TC / 32), dim3(32, 8), 0, stream>>>(w_fc1, wfc1T, TC, 4 * TC);
    transpose_cast_kernel<<<dim3(TC / 32, 4 * TC / 32), dim3(32, 8), 0, stream>>>(w_fc2, wfc2T, 4 * TC, TC);

    gemm_bt_kernel<0><<<dim3(3 * TC / 128, MROWS / 128), 256, 0, stream>>>(
        xb, wqkvT, b_qkv, qkv, MROWS, 3 * TC, TC);
    attn_kernel<<<dim3(16, NH, TB), 256, 0, stream>>>(qkv, yb);
    ln_kernel<float, bf16><<<MROWS, 256, 0, stream>>>(x, (const bf16*)yb, ln1_g, ln1_b, (bf16*)x1);
    gemm_bt_kernel<1><<<dim3(4 * TC / 128, MROWS / 128), 256, 0, stream>>>(
        (const u16*)x1, wfc1T, b_fc1, hb, MROWS, 4 * TC, TC);
    gemm_bt_kernel<0><<<dim3(TC / 128, MROWS / 128), 256, 0, stream>>>(
        hb, wfc2T, b_fc2, mlp, MROWS, TC, 4 * TC);
    ln_kernel<bf16, float><<<MROWS, 256, 0, stream>>>(
        (const bf16*)x1, (const bf16*)mlp, ln2_g, ln2_b, out);
}

// Round 3
// 542.903 us; speedup vs baseline: 1.5423x; 1.1014x over previous
//
#include <hip/hip_runtime.h>
#include <cstdint>
#include <cstddef>

// Problem constants
#define TB 4
#define TT 2048
#define TC 1024
#define NH 16
#define HD 64
#define MROWS (TB * TT)   // 8192

typedef __bf16 bf16;
typedef unsigned short u16;
typedef __bf16 bf16x8 __attribute__((ext_vector_type(8)));
typedef float floatx4 __attribute__((ext_vector_type(4)));
typedef unsigned short ushort8 __attribute__((ext_vector_type(8)));
typedef unsigned short ushort4v __attribute__((ext_vector_type(4)));

#define LOG2E 1.4426950408889634f

static __device__ __forceinline__ u16 f2bfbits(float f) {
    bf16 b = (bf16)f;
    return __builtin_bit_cast(u16, b);
}

#if __has_builtin(__builtin_amdgcn_exp2f)
#define EXP2F(x) __builtin_amdgcn_exp2f(x)
#else
#define EXP2F(x) exp2f(x)
#endif

// async global->LDS 16B (dest = wave-uniform base + lane*16)
static __device__ __forceinline__ void gld_lds16(const u16* g, const u16* lds) {
    __builtin_amdgcn_global_load_lds(
        (const __attribute__((address_space(1))) unsigned int*)(uintptr_t)g,
        (__attribute__((address_space(3))) unsigned int*)(unsigned int)(uintptr_t)lds,
        16, 0, 0);
}

// ---------------------------------------------------------------------------
__global__ void cast_bf16_kernel(const float* __restrict__ in, u16* __restrict__ out, int n4) {
    int i = blockIdx.x * blockDim.x + threadIdx.x;
    if (i < n4) {
        float4 v = reinterpret_cast<const float4*>(in)[i];
        ushort4v o;
        o.x = f2bfbits(v.x); o.y = f2bfbits(v.y); o.z = f2bfbits(v.z); o.w = f2bfbits(v.w);
        reinterpret_cast<ushort4v*>(out)[i] = o;
    }
}

// ---------------------------------------------------------------------------
__global__ void transpose_cast_kernel(const float* __restrict__ in, u16* __restrict__ out,
                                      int K, int N) {
    __shared__ float tile[32][33];
    const int n0 = blockIdx.x * 32, k0 = blockIdx.y * 32;
    const int tx = threadIdx.x, ty = threadIdx.y;
    for (int r = 0; r < 32; r += 8)
        tile[ty + r][tx] = in[(size_t)(k0 + ty + r) * N + n0 + tx];
    __syncthreads();
    for (int r = 0; r < 32; r += 8)
        out[(size_t)(n0 + ty + r) * K + k0 + tx] = f2bfbits(tile[tx][ty + r]);
}

// ---------------------------------------------------------------------------
// GEMM (m97 structure + hoisted pointers + XOR chunk swizzle on LDS layout).
template <int GELU>
__global__ __launch_bounds__(256) void gemm_bt_kernel(
    const u16* __restrict__ A, const u16* __restrict__ Bt,
    const float* __restrict__ bias, u16* __restrict__ Cmat,
    int Nsz, int Ksz)
{
    __shared__ u16 As[128 * 32];
    __shared__ u16 Bs[128 * 32];
    const int tid  = threadIdx.x;
    const int wave = tid >> 6, lane = tid & 63;
    const int quad = lane >> 4, l16 = lane & 15;
    const int wm = (wave >> 1) * 64, wn = (wave & 1) * 64;
    const int m0 = blockIdx.y * 128, n0 = blockIdx.x * 128;

    // staging: physical 16B slot = tid (DMA); fetch the XOR-swizzled logical chunk
    const int rowA = tid >> 2;
    const int colA = ((tid & 3) ^ (rowA & 3)) * 8;
    const u16* ap0 = A  + (size_t)(m0 + rowA) * Ksz + colA;
    const u16* ap1 = ap0 + (size_t)64 * Ksz;
    const u16* bp0 = Bt + (size_t)(n0 + rowA) * Ksz + colA;
    const u16* bp1 = bp0 + (size_t)64 * Ksz;
    u16* const adst0 = As + wave * 512;
    u16* const adst1 = As + 2048 + wave * 512;
    u16* const bdst0 = Bs + wave * 512;
    u16* const bdst1 = Bs + 2048 + wave * 512;

    floatx4 acc[4][4];
#pragma unroll
    for (int i = 0; i < 4; i++)
#pragma unroll
        for (int j = 0; j < 4; j++)
            acc[i][j] = (floatx4){0.f, 0.f, 0.f, 0.f};

    const int s4 = (quad ^ (l16 & 3)) * 8;   // physical chunk offset for frag reads

    for (int k0 = 0; k0 < Ksz; k0 += 32) {
        __syncthreads();
        gld_lds16(ap0, adst0);
        gld_lds16(ap1, adst1);
        gld_lds16(bp0, bdst0);
        gld_lds16(bp1, bdst1);
        ap0 += 32; ap1 += 32; bp0 += 32; bp1 += 32;
        __syncthreads();

        bf16x8 af[4], bfr[4];
#pragma unroll
        for (int i = 0; i < 4; i++)
            af[i] = *reinterpret_cast<const bf16x8*>(As + (wm + i * 16 + l16) * 32 + s4);
#pragma unroll
        for (int j = 0; j < 4; j++)
            bfr[j] = *reinterpret_cast<const bf16x8*>(Bs + (wn + j * 16 + l16) * 32 + s4);
#pragma unroll
        for (int i = 0; i < 4; i++)
#pragma unroll
            for (int j = 0; j < 4; j++)
                acc[i][j] = __builtin_amdgcn_mfma_f32_16x16x32_bf16(af[i], bfr[j], acc[i][j], 0, 0, 0);
    }

    // epilogue: C layout col=lane&15, row=quad*4+reg
#pragma unroll
    for (int i = 0; i < 4; i++) {
        const int row_base = m0 + wm + i * 16 + quad * 4;
#pragma unroll
        for (int j = 0; j < 4; j++) {
            const int col = n0 + wn + j * 16 + l16;
            const float bv = bias[col];
#pragma unroll
            for (int r = 0; r < 4; r++) {
                float v = acc[i][j][r] + bv;
                if (GELU) v = 0.5f * v * (1.0f + erff(v * 0.70710678118f));
                Cmat[(size_t)(row_base + r) * Nsz + col] = f2bfbits(v);
            }
        }
    }
}

// ---------------------------------------------------------------------------
// Flash attention, causal, S^T formulation, k-tile 64, swizzled single-buffer LDS.
__global__ __launch_bounds__(256, 4) void attn_kernel(const u16* __restrict__ qkv,
                                                      u16* __restrict__ y)
{
    __shared__ u16 Ks[64 * 64];     // [key][d], chunk-swizzled: pc = c ^ (key&7)
    __shared__ u16 Vt[64 * 64];     // [d][key], dword-swizzled
    __shared__ u16 Pw[4][16 * 64];  // per-wave [q][key], chunk-swizzled: pc = c ^ (q&7)
    const int tid  = threadIdx.x;
    const int wave = tid >> 6, lane = tid & 63;
    const int quad = lane >> 4, l16 = lane & 15;
    const int l7   = l16 & 7;
    const int h = blockIdx.y, b = blockIdx.z;
    const int rowbase = b * TT;
    const int S3C = 3 * TC;

    // staging roles
    const int srow = tid >> 3;                        // 0..31
    const int kc8  = (tid & 7) * 8;                   // d-chunk for K/V global loads
    const int pcK  = ((tid & 7) ^ (srow & 7)) * 8;    // K physical chunk (u16 offset)
    const int pvb  = (srow + ((tid & 7) << 2)) & 31;  // V physical dword base
    // compute-side swizzled offsets
    const int pcr  = (quad ^ l7) * 8;                 // Ks/Pw frag chunk (u16 offset)
    unsigned int* const vtw = (unsigned int*)Vt;
    const int wavq = wave * 16 + l16;                 // q local to 64-row block

    for (int pass = 0; pass < 2; pass++) {
        const int qt  = pass ? (31 - (int)blockIdx.x) : (int)blockIdx.x;
        const int q0b = qt * 64;
        const int q0w = q0b + wave * 16;
        const int kend = q0b + 64;

        // Q as B-operand frags, pre-scaled by 0.125*log2(e)
        bf16x8 qf0, qf1;
        {
            const u16* qrow = qkv + (size_t)(rowbase + q0w + l16) * S3C + h * HD + quad * 8;
            bf16x8 t0 = *reinterpret_cast<const bf16x8*>(qrow);
            bf16x8 t1 = *reinterpret_cast<const bf16x8*>(qrow + 32);
#pragma unroll
            for (int i = 0; i < 8; i++) {
                t0[i] = (bf16)((float)t0[i] * (0.125f * LOG2E));
                t1[i] = (bf16)((float)t1[i] * (0.125f * LOG2E));
            }
            qf0 = t0; qf1 = t1;
        }

        float m_s = -__builtin_inff(), l_s = 0.f;
        floatx4 o_acc[4];
#pragma unroll
        for (int n = 0; n < 4; n++) o_acc[n] = (floatx4){0.f, 0.f, 0.f, 0.f};

        // prefetch tile 0 into registers
        ushort8 kr0, kr1, vr0, vr1;
        {
            const u16* kb = qkv + (size_t)(rowbase + srow) * S3C + TC + h * HD + kc8;
            kr0 = *reinterpret_cast<const ushort8*>(kb);
            kr1 = *reinterpret_cast<const ushort8*>(kb + (size_t)32 * S3C);
            const u16* vb = qkv + (size_t)(rowbase + 2 * srow) * S3C + 2 * TC + h * HD + kc8;
            vr0 = *reinterpret_cast<const ushort8*>(vb);
            vr1 = *reinterpret_cast<const ushort8*>(vb + S3C);
        }

        for (int k0 = 0; k0 < kend; k0 += 64) {
            __syncthreads();   // prior-iter/pass LDS reads complete
            *reinterpret_cast<ushort8*>(Ks + srow * 64 + pcK)        = kr0;
            *reinterpret_cast<ushort8*>(Ks + (srow + 32) * 64 + pcK) = kr1;
#pragma unroll
            for (int j = 0; j < 8; j++) {
                unsigned int pk = (unsigned int)vr0[j] | ((unsigned int)vr1[j] << 16);
                vtw[(kc8 + j) * 32 + (pvb ^ (j << 2))] = pk;
            }
            __syncthreads();

            if (k0 + 64 < kend) {   // prefetch next tile
                const int kn = k0 + 64;
                const u16* kb = qkv + (size_t)(rowbase + kn + srow) * S3C + TC + h * HD + kc8;
                kr0 = *reinterpret_cast<const ushort8*>(kb);
                kr1 = *reinterpret_cast<const ushort8*>(kb + (size_t)32 * S3C);
                const u16* vb = qkv + (size_t)(rowbase + kn + 2 * srow) * S3C + 2 * TC + h * HD + kc8;
                vr0 = *reinterpret_cast<const ushort8*>(vb);
                vr1 = *reinterpret_cast<const ushort8*>(vb + S3C);
            }

            // S^T = K · Q^T (4 subtiles of 16 keys)
            floatx4 st[4];
#pragma unroll
            for (int t = 0; t < 4; t++) {
                const u16* krowp = Ks + (t * 16 + l16) * 64;
                bf16x8 ka  = *reinterpret_cast<const bf16x8*>(krowp + pcr);
                bf16x8 kb2 = *reinterpret_cast<const bf16x8*>(krowp + (pcr ^ 32));
                floatx4 s = (floatx4){0.f, 0.f, 0.f, 0.f};
                s = __builtin_amdgcn_mfma_f32_16x16x32_bf16(ka, qf0, s, 0, 0, 0);
                s = __builtin_amdgcn_mfma_f32_16x16x32_bf16(kb2, qf1, s, 0, 0, 0);
                st[t] = s;
            }
            float v[16];
            if (k0 == q0b) {   // diagonal tile: causal mask (wave-uniform branch)
#pragma unroll
                for (int t = 0; t < 4; t++)
#pragma unroll
                    for (int r = 0; r < 4; r++)
                        v[t * 4 + r] = (t * 16 + quad * 4 + r > wavq) ? -__builtin_inff()
                                                                      : st[t][r];
            } else {
#pragma unroll
                for (int t = 0; t < 4; t++)
#pragma unroll
                    for (int r = 0; r < 4; r++)
                        v[t * 4 + r] = st[t][r];
            }
            // online softmax (log2 domain); per-lane q = wavq, reduce across quads
            float mx = v[0];
#pragma unroll
            for (int i = 1; i < 16; i++) mx = fmaxf(mx, v[i]);
            mx = fmaxf(mx, __shfl_xor(mx, 16));
            mx = fmaxf(mx, __shfl_xor(mx, 32));
            const float mnew  = fmaxf(m_s, mx);
            const float alpha = EXP2F(m_s - mnew);
            float rs = 0.f;
            u16* const pwb = Pw[wave] + l16 * 64;
#pragma unroll
            for (int t = 0; t < 4; t++) {
                float p0 = EXP2F(v[t * 4 + 0] - mnew);
                float p1 = EXP2F(v[t * 4 + 1] - mnew);
                float p2 = EXP2F(v[t * 4 + 2] - mnew);
                float p3 = EXP2F(v[t * 4 + 3] - mnew);
                rs += (p0 + p1) + (p2 + p3);
                ushort4v pk;
                pk.x = f2bfbits(p0); pk.y = f2bfbits(p1);
                pk.z = f2bfbits(p2); pk.w = f2bfbits(p3);
                *reinterpret_cast<ushort4v*>(
                    pwb + ((2 * t + (quad >> 1)) ^ l7) * 8 + (quad & 1) * 4) = pk;
            }
            rs += __shfl_xor(rs, 16);
            rs += __shfl_xor(rs, 32);
            l_s = l_s * alpha + rs;
            m_s = mnew;
#pragma unroll
            for (int n = 0; n < 4; n++) o_acc[n] *= alpha;

            // PV: O^T += V^T · P^T
            bf16x8 pf0 = *reinterpret_cast<const bf16x8*>(pwb + pcr);
            bf16x8 pf1 = *reinterpret_cast<const bf16x8*>(pwb + (pcr ^ 32));
#pragma unroll
            for (int n = 0; n < 4; n++) {
                const int dr  = n * 16 + l16;
                const int pd0 = ((4 * (quad + 2 * n + (l16 >> 3))) & 31) ^ (l7 << 2);
                bf16x8 vf0 = *reinterpret_cast<const bf16x8*>(vtw + dr * 32 + pd0);
                bf16x8 vf1 = *reinterpret_cast<const bf16x8*>(vtw + dr * 32 + (pd0 ^ 16));
                o_acc[n] = __builtin_amdgcn_mfma_f32_16x16x32_bf16(vf0, pf0, o_acc[n], 0, 0, 0);
                o_acc[n] = __builtin_amdgcn_mfma_f32_16x16x32_bf16(vf1, pf1, o_acc[n], 0, 0, 0);
            }
        }

        // write O^T: col=l16=q, row=quad*4+r=d_local
        const float li = 1.0f / l_s;
        u16* yrow = y + (size_t)(rowbase + q0w + l16) * TC + h * HD;
#pragma unroll
        for (int n = 0; n < 4; n++) {
            ushort4v ov;
            ov.x = f2bfbits(o_acc[n][0] * li);
            ov.y = f2bfbits(o_acc[n][1] * li);
            ov.z = f2bfbits(o_acc[n][2] * li);
            ov.w = f2bfbits(o_acc[n][3] * li);
            *reinterpret_cast<ushort4v*>(yrow + n * 16 + quad * 4) = ov;
        }
    }
}

// ---------------------------------------------------------------------------
template <typename AT, typename OT>
__global__ __launch_bounds__(256) void ln_kernel(
    const AT* __restrict__ a, const bf16* __restrict__ bres,
    const float* __restrict__ g, const float* __restrict__ be,
    OT* __restrict__ out)
{
    const int row = blockIdx.x;
    const int tid = threadIdx.x;
    const size_t base = (size_t)row * TC;
    float v[4];
    for (int i = 0; i < 4; i++) {
        const int c = tid + i * 256;
        v[i] = (float)a[base + c] + (float)bres[base + c];
    }
    float s  = v[0] + v[1] + v[2] + v[3];
    float sq = v[0]*v[0] + v[1]*v[1] + v[2]*v[2] + v[3]*v[3];
    for (int off = 32; off >= 1; off >>= 1) {
        s  += __shfl_xor(s, off, 64);
        sq += __shfl_xor(sq, off, 64);
    }
    __shared__ float red[8];
    const int wv = tid >> 6, lane = tid & 63;
    if (lane == 0) { red[wv] = s; red[4 + wv] = sq; }
    __syncthreads();
    s  = red[0] + red[1] + red[2] + red[3];
    sq = red[4] + red[5] + red[6] + red[7];
    const float mu   = s * (1.0f / TC);
    const float var  = sq * (1.0f / TC) - mu * mu;
    const float rsig = rsqrtf(var + 1e-5f);
    for (int i = 0; i < 4; i++) {
        const int c = tid + i * 256;
        out[base + c] = (OT)((v[i] - mu) * rsig * g[c] + be[c]);
    }
}

// ---------------------------------------------------------------------------
extern "C" void kernel_launch(void* const* d_in, const int* in_sizes, int n_in,
                              void* d_out, int out_size, void* d_ws, size_t ws_size,
                              hipStream_t stream)
{
    const float* x     = (const float*)d_in[0];
    const float* w_qkv = (const float*)d_in[1];
    const float* b_qkv = (const float*)d_in[2];
    const float* ln1_g = (const float*)d_in[3];
    const float* ln1_b = (const float*)d_in[4];
    const float* w_fc1 = (const float*)d_in[5];
    const float* b_fc1 = (const float*)d_in[6];
    const float* w_fc2 = (const float*)d_in[7];
    const float* b_fc2 = (const float*)d_in[8];
    const float* ln2_g = (const float*)d_in[9];
    const float* ln2_b = (const float*)d_in[10];
    float* out = (float*)d_out;

    char* ws = (char*)d_ws;
    const size_t MB = 1ull << 20;
    u16* xb    = (u16*)(ws + 0);        // [8192][1024]  16 MB
    u16* wqkvT = (u16*)(ws + 16 * MB);  // [3072][1024]   6 MB
    u16* wfc1T = (u16*)(ws + 22 * MB);  // [4096][1024]   8 MB
    u16* wfc2T = (u16*)(ws + 30 * MB);  // [1024][4096]   8 MB
    u16* qkv   = (u16*)(ws + 38 * MB);  // [8192][3072]  48 MB
    u16* yb    = (u16*)(ws + 86 * MB);  // [8192][1024]  16 MB
    u16* x1    = (u16*)(ws + 102 * MB); // [8192][1024]  16 MB
    u16* hb    = (u16*)(ws + 118 * MB); // [8192][4096]  64 MB
    u16* mlp   = (u16*)(ws + 38 * MB);  // reuse qkv region

    cast_bf16_kernel<<<(MROWS * TC / 4 + 255) / 256, 256, 0, stream>>>(x, xb, MROWS * TC / 4);
    transpose_cast_kernel<<<dim3(3 * TC / 32, TC / 32), dim3(32, 8), 0, stream>>>(w_qkv, wqkvT, TC, 3 * TC);
    transpose_cast_kernel<<<dim3(4 * TC / 32, TC / 32), dim3(32, 8), 0, stream>>>(w_fc1, wfc1T, TC, 4 * TC);
    transpose_cast_kernel<<<dim3(TC / 32, 4 * TC / 32), dim3(32, 8), 0, stream>>>(w_fc2, wfc2T, 4 * TC, TC);

    gemm_bt_kernel<0><<<dim3(3 * TC / 128, MROWS / 128), 256, 0, stream>>>(
        xb, wqkvT, b_qkv, qkv, 3 * TC, TC);
    attn_kernel<<<dim3(16, NH, TB), 256, 0, stream>>>(qkv, yb);
    ln_kernel<float, bf16><<<MROWS, 256, 0, stream>>>(x, (const bf16*)yb, ln1_g, ln1_b, (bf16*)x1);
    gemm_bt_kernel<1><<<dim3(4 * TC / 128, MROWS / 128), 256, 0, stream>>>(
        (const u16*)x1, wfc1T, b_fc1, hb, 4 * TC, TC);
    gemm_bt_kernel<0><<<dim3(TC / 128, MROWS / 128), 256, 0, stream>>>(
        hb, wfc2T, b_fc2, mlp, TC, 4 * TC);
    ln_kernel<bf16, float><<<MROWS, 256, 0, stream>>>(
        (const bf16*)x1, (const bf16*)mlp, ln2_g, ln2_b, out);
}

// Round 4
// 495.518 us; speedup vs baseline: 1.6898x; 1.0956x over previous
//
#include <hip/hip_runtime.h>
#include <cstdint>
#include <cstddef>

// Problem constants
#define TB 4
#define TT 2048
#define TC 1024
#define NH 16
#define HD 64
#define MROWS (TB * TT)   // 8192

typedef __bf16 bf16;
typedef unsigned short u16;
typedef __bf16 bf16x8 __attribute__((ext_vector_type(8)));
typedef float floatx4 __attribute__((ext_vector_type(4)));
typedef unsigned short ushort8 __attribute__((ext_vector_type(8)));
typedef unsigned short ushort4v __attribute__((ext_vector_type(4)));

#define LOG2E 1.4426950408889634f

static __device__ __forceinline__ u16 f2bfbits(float f) {
    bf16 b = (bf16)f;
    return __builtin_bit_cast(u16, b);
}

#if __has_builtin(__builtin_amdgcn_exp2f)
#define EXP2F(x) __builtin_amdgcn_exp2f(x)
#else
#define EXP2F(x) exp2f(x)
#endif

// async global->LDS 16B (dest = wave-uniform base + lane*16)
static __device__ __forceinline__ void gld_lds16(const u16* g, const u16* lds) {
    __builtin_amdgcn_global_load_lds(
        (const __attribute__((address_space(1))) unsigned int*)(uintptr_t)g,
        (__attribute__((address_space(3))) unsigned int*)(unsigned int)(uintptr_t)lds,
        16, 0, 0);
}

// ---------------------------------------------------------------------------
__global__ void cast_bf16_kernel(const float* __restrict__ in, u16* __restrict__ out, int n4) {
    int i = blockIdx.x * blockDim.x + threadIdx.x;
    if (i < n4) {
        float4 v = reinterpret_cast<const float4*>(in)[i];
        ushort4v o;
        o.x = f2bfbits(v.x); o.y = f2bfbits(v.y); o.z = f2bfbits(v.z); o.w = f2bfbits(v.w);
        reinterpret_cast<ushort4v*>(out)[i] = o;
    }
}

// ---------------------------------------------------------------------------
__global__ void transpose_cast_kernel(const float* __restrict__ in, u16* __restrict__ out,
                                      int K, int N) {
    __shared__ float tile[32][33];
    const int n0 = blockIdx.x * 32, k0 = blockIdx.y * 32;
    const int tx = threadIdx.x, ty = threadIdx.y;
    for (int r = 0; r < 32; r += 8)
        tile[ty + r][tx] = in[(size_t)(k0 + ty + r) * N + n0 + tx];
    __syncthreads();
    for (int r = 0; r < 32; r += 8)
        out[(size_t)(n0 + ty + r) * K + k0 + tx] = f2bfbits(tile[tx][ty + r]);
}

// ---------------------------------------------------------------------------
// GEMM: 128x128 tile, BK=64, global_load_lds staging, XOR-swizzled LDS
// (8 chunks of 16B per 64-elem row: physical chunk = logical ^ (row&7)).
// Fast tanh-GELU epilogue (max dev from exact erf-GELU ~3e-4, below bf16 noise).
template <int GELU>
__global__ __launch_bounds__(256) void gemm_bt_kernel(
    const u16* __restrict__ A, const u16* __restrict__ Bt,
    const float* __restrict__ bias, u16* __restrict__ Cmat,
    int Nsz, int Ksz)
{
    __shared__ u16 As[128 * 64];
    __shared__ u16 Bs[128 * 64];
    const int tid  = threadIdx.x;
    const int wave = tid >> 6, lane = tid & 63;
    const int quad = lane >> 4, l16 = lane & 15;
    const int wm = (wave >> 1) * 64, wn = (wave & 1) * 64;
    const int m0 = blockIdx.y * 128, n0 = blockIdx.x * 128;

    // staging: DMA d (d=0..3) covers physical 16B slots (wave*4+d)*64 + lane.
    // slot s -> row = s>>3, phys chunk = s&7; logical chunk = (s&7) ^ (row&7).
    // row&7 == lane>>3 for all d, so source col = ((lane&7) ^ (lane>>3)) * 8.
    const int srow = lane >> 3;
    const int scol = ((lane & 7) ^ srow) * 8;
    const u16* ap = A  + (size_t)(m0 + wave * 32 + srow) * Ksz + scol;
    const u16* bp = Bt + (size_t)(n0 + wave * 32 + srow) * Ksz + scol;
    const size_t dstep = (size_t)8 * Ksz;   // DMA d source offset = d*dstep

    floatx4 acc[4][4];
#pragma unroll
    for (int i = 0; i < 4; i++)
#pragma unroll
        for (int j = 0; j < 4; j++)
            acc[i][j] = (floatx4){0.f, 0.f, 0.f, 0.f};

    const int l7 = l16 & 7;

    for (int k0 = 0; k0 < Ksz; k0 += 64) {
        __syncthreads();
#pragma unroll
        for (int d = 0; d < 4; d++) {
            gld_lds16(ap + d * dstep, As + (wave * 4 + d) * 512);
            gld_lds16(bp + d * dstep, Bs + (wave * 4 + d) * 512);
        }
        ap += 64; bp += 64;
        __syncthreads();

#pragma unroll
        for (int t = 0; t < 2; t++) {
            const int po = ((t * 4 + quad) ^ l7) * 8;
            bf16x8 af[4], bfr[4];
#pragma unroll
            for (int i = 0; i < 4; i++)
                af[i] = *reinterpret_cast<const bf16x8*>(As + (wm + i * 16 + l16) * 64 + po);
#pragma unroll
            for (int j = 0; j < 4; j++)
                bfr[j] = *reinterpret_cast<const bf16x8*>(Bs + (wn + j * 16 + l16) * 64 + po);
#pragma unroll
            for (int i = 0; i < 4; i++)
#pragma unroll
                for (int j = 0; j < 4; j++)
                    acc[i][j] = __builtin_amdgcn_mfma_f32_16x16x32_bf16(af[i], bfr[j], acc[i][j], 0, 0, 0);
        }
    }

    // epilogue: C layout col=lane&15, row=quad*4+reg
#pragma unroll
    for (int i = 0; i < 4; i++) {
        const int row_base = m0 + wm + i * 16 + quad * 4;
#pragma unroll
        for (int j = 0; j < 4; j++) {
            const int col = n0 + wn + j * 16 + l16;
            const float bv = bias[col];
#pragma unroll
            for (int r = 0; r < 4; r++) {
                float v = acc[i][j][r] + bv;
                if (GELU) {
                    // gelu(v) = v * e/(e+1), e = exp(2*u), u = sqrt(2/pi)(v+0.044715v^3)
                    float u = v * (0.7978845608f + 0.0356774081f * v * v);
                    float e = EXP2F(u * (2.0f * LOG2E));
                    v = v - v * __builtin_amdgcn_rcpf(e + 1.0f);
                }
                Cmat[(size_t)(row_base + r) * Nsz + col] = f2bfbits(v);
            }
        }
    }
}

// ---------------------------------------------------------------------------
// Flash attention, causal, S^T formulation, k-tile 64, swizzled single-buffer LDS.
__global__ __launch_bounds__(256, 4) void attn_kernel(const u16* __restrict__ qkv,
                                                      u16* __restrict__ y)
{
    __shared__ u16 Ks[64 * 64];     // [key][d], chunk-swizzled: pc = c ^ (key&7)
    __shared__ u16 Vt[64 * 64];     // [d][key], dword-swizzled
    __shared__ u16 Pw[4][16 * 64];  // per-wave [q][key], chunk-swizzled: pc = c ^ (q&7)
    const int tid  = threadIdx.x;
    const int wave = tid >> 6, lane = tid & 63;
    const int quad = lane >> 4, l16 = lane & 15;
    const int l7   = l16 & 7;
    const int h = blockIdx.y, b = blockIdx.z;
    const int rowbase = b * TT;
    const int S3C = 3 * TC;

    // staging roles
    const int srow = tid >> 3;                        // 0..31
    const int kc8  = (tid & 7) * 8;                   // d-chunk for K/V global loads
    const int pcK  = ((tid & 7) ^ (srow & 7)) * 8;    // K physical chunk (u16 offset)
    const int pvb  = (srow + ((tid & 7) << 2)) & 31;  // V physical dword base
    const int pcr  = (quad ^ l7) * 8;                 // Ks/Pw frag chunk (u16 offset)
    unsigned int* const vtw = (unsigned int*)Vt;
    const int wavq = wave * 16 + l16;                 // q local to 64-row block

    for (int pass = 0; pass < 2; pass++) {
        const int qt  = pass ? (31 - (int)blockIdx.x) : (int)blockIdx.x;
        const int q0b = qt * 64;
        const int q0w = q0b + wave * 16;
        const int kend = q0b + 64;

        // Q as B-operand frags, pre-scaled by 0.125*log2(e)
        bf16x8 qf0, qf1;
        {
            const u16* qrow = qkv + (size_t)(rowbase + q0w + l16) * S3C + h * HD + quad * 8;
            bf16x8 t0 = *reinterpret_cast<const bf16x8*>(qrow);
            bf16x8 t1 = *reinterpret_cast<const bf16x8*>(qrow + 32);
#pragma unroll
            for (int i = 0; i < 8; i++) {
                t0[i] = (bf16)((float)t0[i] * (0.125f * LOG2E));
                t1[i] = (bf16)((float)t1[i] * (0.125f * LOG2E));
            }
            qf0 = t0; qf1 = t1;
        }

        float m_s = -__builtin_inff(), l_s = 0.f;
        floatx4 o_acc[4];
#pragma unroll
        for (int n = 0; n < 4; n++) o_acc[n] = (floatx4){0.f, 0.f, 0.f, 0.f};

        // prefetch tile 0 into registers
        ushort8 kr0, kr1, vr0, vr1;
        {
            const u16* kb = qkv + (size_t)(rowbase + srow) * S3C + TC + h * HD + kc8;
            kr0 = *reinterpret_cast<const ushort8*>(kb);
            kr1 = *reinterpret_cast<const ushort8*>(kb + (size_t)32 * S3C);
            const u16* vb = qkv + (size_t)(rowbase + 2 * srow) * S3C + 2 * TC + h * HD + kc8;
            vr0 = *reinterpret_cast<const ushort8*>(vb);
            vr1 = *reinterpret_cast<const ushort8*>(vb + S3C);
        }

        for (int k0 = 0; k0 < kend; k0 += 64) {
            __syncthreads();
            *reinterpret_cast<ushort8*>(Ks + srow * 64 + pcK)        = kr0;
            *reinterpret_cast<ushort8*>(Ks + (srow + 32) * 64 + pcK) = kr1;
#pragma unroll
            for (int j = 0; j < 8; j++) {
                unsigned int pk = (unsigned int)vr0[j] | ((unsigned int)vr1[j] << 16);
                vtw[(kc8 + j) * 32 + (pvb ^ (j << 2))] = pk;
            }
            __syncthreads();

            if (k0 + 64 < kend) {
                const int kn = k0 + 64;
                const u16* kb = qkv + (size_t)(rowbase + kn + srow) * S3C + TC + h * HD + kc8;
                kr0 = *reinterpret_cast<const ushort8*>(kb);
                kr1 = *reinterpret_cast<const ushort8*>(kb + (size_t)32 * S3C);
                const u16* vb = qkv + (size_t)(rowbase + kn + 2 * srow) * S3C + 2 * TC + h * HD + kc8;
                vr0 = *reinterpret_cast<const ushort8*>(vb);
                vr1 = *reinterpret_cast<const ushort8*>(vb + S3C);
            }

            // S^T = K · Q^T (4 subtiles of 16 keys)
            floatx4 st[4];
#pragma unroll
            for (int t = 0; t < 4; t++) {
                const u16* krowp = Ks + (t * 16 + l16) * 64;
                bf16x8 ka  = *reinterpret_cast<const bf16x8*>(krowp + pcr);
                bf16x8 kb2 = *reinterpret_cast<const bf16x8*>(krowp + (pcr ^ 32));
                floatx4 s = (floatx4){0.f, 0.f, 0.f, 0.f};
                s = __builtin_amdgcn_mfma_f32_16x16x32_bf16(ka, qf0, s, 0, 0, 0);
                s = __builtin_amdgcn_mfma_f32_16x16x32_bf16(kb2, qf1, s, 0, 0, 0);
                st[t] = s;
            }
            float v[16];
            if (k0 == q0b) {   // diagonal tile: causal mask (wave-uniform branch)
#pragma unroll
                for (int t = 0; t < 4; t++)
#pragma unroll
                    for (int r = 0; r < 4; r++)
                        v[t * 4 + r] = (t * 16 + quad * 4 + r > wavq) ? -__builtin_inff()
                                                                      : st[t][r];
            } else {
#pragma unroll
                for (int t = 0; t < 4; t++)
#pragma unroll
                    for (int r = 0; r < 4; r++)
                        v[t * 4 + r] = st[t][r];
            }
            float mx = v[0];
#pragma unroll
            for (int i = 1; i < 16; i++) mx = fmaxf(mx, v[i]);
            mx = fmaxf(mx, __shfl_xor(mx, 16));
            mx = fmaxf(mx, __shfl_xor(mx, 32));
            const float mnew  = fmaxf(m_s, mx);
            const float alpha = EXP2F(m_s - mnew);
            float rs = 0.f;
            u16* const pwb = Pw[wave] + l16 * 64;
#pragma unroll
            for (int t = 0; t < 4; t++) {
                float p0 = EXP2F(v[t * 4 + 0] - mnew);
                float p1 = EXP2F(v[t * 4 + 1] - mnew);
                float p2 = EXP2F(v[t * 4 + 2] - mnew);
                float p3 = EXP2F(v[t * 4 + 3] - mnew);
                rs += (p0 + p1) + (p2 + p3);
                ushort4v pk;
                pk.x = f2bfbits(p0); pk.y = f2bfbits(p1);
                pk.z = f2bfbits(p2); pk.w = f2bfbits(p3);
                *reinterpret_cast<ushort4v*>(
                    pwb + ((2 * t + (quad >> 1)) ^ l7) * 8 + (quad & 1) * 4) = pk;
            }
            rs += __shfl_xor(rs, 16);
            rs += __shfl_xor(rs, 32);
            l_s = l_s * alpha + rs;
            m_s = mnew;
#pragma unroll
            for (int n = 0; n < 4; n++) o_acc[n] *= alpha;

            // PV: O^T += V^T · P^T
            bf16x8 pf0 = *reinterpret_cast<const bf16x8*>(pwb + pcr);
            bf16x8 pf1 = *reinterpret_cast<const bf16x8*>(pwb + (pcr ^ 32));
#pragma unroll
            for (int n = 0; n < 4; n++) {
                const int dr  = n * 16 + l16;
                const int pd0 = ((4 * (quad + 2 * n + (l16 >> 3))) & 31) ^ (l7 << 2);
                bf16x8 vf0 = *reinterpret_cast<const bf16x8*>(vtw + dr * 32 + pd0);
                bf16x8 vf1 = *reinterpret_cast<const bf16x8*>(vtw + dr * 32 + (pd0 ^ 16));
                o_acc[n] = __builtin_amdgcn_mfma_f32_16x16x32_bf16(vf0, pf0, o_acc[n], 0, 0, 0);
                o_acc[n] = __builtin_amdgcn_mfma_f32_16x16x32_bf16(vf1, pf1, o_acc[n], 0, 0, 0);
            }
        }

        // write O^T: col=l16=q, row=quad*4+r=d_local
        const float li = 1.0f / l_s;
        u16* yrow = y + (size_t)(rowbase + q0w + l16) * TC + h * HD;
#pragma unroll
        for (int n = 0; n < 4; n++) {
            ushort4v ov;
            ov.x = f2bfbits(o_acc[n][0] * li);
            ov.y = f2bfbits(o_acc[n][1] * li);
            ov.z = f2bfbits(o_acc[n][2] * li);
            ov.w = f2bfbits(o_acc[n][3] * li);
            *reinterpret_cast<ushort4v*>(yrow + n * 16 + quad * 4) = ov;
        }
    }
}

// ---------------------------------------------------------------------------
template <typename AT, typename OT>
__global__ __launch_bounds__(256) void ln_kernel(
    const AT* __restrict__ a, const bf16* __restrict__ bres,
    const float* __restrict__ g, const float* __restrict__ be,
    OT* __restrict__ out)
{
    const int row = blockIdx.x;
    const int tid = threadIdx.x;
    const size_t base = (size_t)row * TC;
    float v[4];
    for (int i = 0; i < 4; i++) {
        const int c = tid + i * 256;
        v[i] = (float)a[base + c] + (float)bres[base + c];
    }
    float s  = v[0] + v[1] + v[2] + v[3];
    float sq = v[0]*v[0] + v[1]*v[1] + v[2]*v[2] + v[3]*v[3];
    for (int off = 32; off >= 1; off >>= 1) {
        s  += __shfl_xor(s, off, 64);
        sq += __shfl_xor(sq, off, 64);
    }
    __shared__ float red[8];
    const int wv = tid >> 6, lane = tid & 63;
    if (lane == 0) { red[wv] = s; red[4 + wv] = sq; }
    __syncthreads();
    s  = red[0] + red[1] + red[2] + red[3];
    sq = red[4] + red[5] + red[6] + red[7];
    const float mu   = s * (1.0f / TC);
    const float var  = sq * (1.0f / TC) - mu * mu;
    const float rsig = rsqrtf(var + 1e-5f);
    for (int i = 0; i < 4; i++) {
        const int c = tid + i * 256;
        out[base + c] = (OT)((v[i] - mu) * rsig * g[c] + be[c]);
    }
}

// ---------------------------------------------------------------------------
extern "C" void kernel_launch(void* const* d_in, const int* in_sizes, int n_in,
                              void* d_out, int out_size, void* d_ws, size_t ws_size,
                              hipStream_t stream)
{
    const float* x     = (const float*)d_in[0];
    const float* w_qkv = (const float*)d_in[1];
    const float* b_qkv = (const float*)d_in[2];
    const float* ln1_g = (const float*)d_in[3];
    const float* ln1_b = (const float*)d_in[4];
    const float* w_fc1 = (const float*)d_in[5];
    const float* b_fc1 = (const float*)d_in[6];
    const float* w_fc2 = (const float*)d_in[7];
    const float* b_fc2 = (const float*)d_in[8];
    const float* ln2_g = (const float*)d_in[9];
    const float* ln2_b = (const float*)d_in[10];
    float* out = (float*)d_out;

    char* ws = (char*)d_ws;
    const size_t MB = 1ull << 20;
    u16* xb    = (u16*)(ws + 0);        // [8192][1024]  16 MB
    u16* wqkvT = (u16*)(ws + 16 * MB);  // [3072][1024]   6 MB
    u16* wfc1T = (u16*)(ws + 22 * MB);  // [4096][1024]   8 MB
    u16* wfc2T = (u16*)(ws + 30 * MB);  // [1024][4096]   8 MB
    u16* qkv   = (u16*)(ws + 38 * MB);  // [8192][3072]  48 MB
    u16* yb    = (u16*)(ws + 86 * MB);  // [8192][1024]  16 MB
    u16* x1    = (u16*)(ws + 102 * MB); // [8192][1024]  16 MB
    u16* hb    = (u16*)(ws + 118 * MB); // [8192][4096]  64 MB
    u16* mlp   = (u16*)(ws + 38 * MB);  // reuse qkv region

    cast_bf16_kernel<<<(MROWS * TC / 4 + 255) / 256, 256, 0, stream>>>(x, xb, MROWS * TC / 4);
    transpose_cast_kernel<<<dim3(3 * TC / 32, TC / 32), dim3(32, 8), 0, stream>>>(w_qkv, wqkvT, TC, 3 * TC);
    transpose_cast_kernel<<<dim3(4 * TC / 32, TC / 32), dim3(32, 8), 0, stream>>>(w_fc1, wfc1T, TC, 4 * TC);
    transpose_cast_kernel<<<dim3(TC / 32, 4 * TC / 32), dim3(32, 8), 0, stream>>>(w_fc2, wfc2T, 4 * TC, TC);

    gemm_bt_kernel<0><<<dim3(3 * TC / 128, MROWS / 128), 256, 0, stream>>>(
        xb, wqkvT, b_qkv, qkv, 3 * TC, TC);
    attn_kernel<<<dim3(16, NH, TB), 256, 0, stream>>>(qkv, yb);
    ln_kernel<float, bf16><<<MROWS, 256, 0, stream>>>(x, (const bf16*)yb, ln1_g, ln1_b, (bf16*)x1);
    gemm_bt_kernel<1><<<dim3(4 * TC / 128, MROWS / 128), 256, 0, stream>>>(
        (const u16*)x1, wfc1T, b_fc1, hb, 4 * TC, TC);
    gemm_bt_kernel<0><<<dim3(TC / 128, MROWS / 128), 256, 0, stream>>>(
        hb, wfc2T, b_fc2, mlp, TC, 4 * TC);
    ln_kernel<bf16, float><<<MROWS, 256, 0, stream>>>(
        (const bf16*)x1, (const bf16*)mlp, ln2_g, ln2_b, out);
}

// Round 5
// 465.399 us; speedup vs baseline: 1.7992x; 1.0647x over previous
//
#include <hip/hip_runtime.h>
#include <cstdint>
#include <cstddef>

// Problem constants
#define TB 4
#define TT 2048
#define TC 1024
#define NH 16
#define HD 64
#define MROWS (TB * TT)   // 8192

typedef __bf16 bf16;
typedef unsigned short u16;
typedef __bf16 bf16x8 __attribute__((ext_vector_type(8)));
typedef float floatx4 __attribute__((ext_vector_type(4)));
typedef unsigned short ushort8 __attribute__((ext_vector_type(8)));
typedef unsigned short ushort4v __attribute__((ext_vector_type(4)));

#define LOG2E 1.4426950408889634f

static __device__ __forceinline__ u16 f2bfbits(float f) {
    bf16 b = (bf16)f;
    return __builtin_bit_cast(u16, b);
}

#if __has_builtin(__builtin_amdgcn_exp2f)
#define EXP2F(x) __builtin_amdgcn_exp2f(x)
#else
#define EXP2F(x) exp2f(x)
#endif

// async global->LDS 16B (dest = wave-uniform base + lane*16)
static __device__ __forceinline__ void gld_lds16(const u16* g, const u16* lds) {
    __builtin_amdgcn_global_load_lds(
        (const __attribute__((address_space(1))) unsigned int*)(uintptr_t)g,
        (__attribute__((address_space(3))) unsigned int*)(unsigned int)(uintptr_t)lds,
        16, 0, 0);
}

// ---------------------------------------------------------------------------
// Unified prep: x cast (blocks 0..8191) + three weight transposes.
__global__ __launch_bounds__(256) void prep_kernel(
    const float* __restrict__ x, u16* __restrict__ xb,
    const float* __restrict__ w_qkv, u16* __restrict__ wqkvT,
    const float* __restrict__ w_fc1, u16* __restrict__ wfc1T,
    const float* __restrict__ w_fc2, u16* __restrict__ wfc2T)
{
    const int tid = threadIdx.x;
    int blk = blockIdx.x;
    if (blk < 8192) {   // cast: whole block uniform path
        const int i = blk * 256 + tid;
        float4 v = reinterpret_cast<const float4*>(x)[i];
        ushort4v o;
        o.x = f2bfbits(v.x); o.y = f2bfbits(v.y); o.z = f2bfbits(v.z); o.w = f2bfbits(v.w);
        reinterpret_cast<ushort4v*>(xb)[i] = o;
        return;
    }
    blk -= 8192;
    const float* in; u16* out; int K, N, bx, by;
    if (blk < 3072)      { in = w_qkv; out = wqkvT; K = TC;     N = 3 * TC; bx = blk % 96;  by = blk / 96; }
    else if (blk < 7168) { blk -= 3072; in = w_fc1; out = wfc1T; K = TC;    N = 4 * TC; bx = blk & 127; by = blk >> 7; }
    else                 { blk -= 7168; in = w_fc2; out = wfc2T; K = 4 * TC; N = TC;    bx = blk & 31;  by = blk >> 5; }
    __shared__ float tile[32][33];
    const int n0 = bx * 32, k0 = by * 32;
    const int tx = tid & 31, ty = tid >> 5;   // 32 x 8
    for (int r = 0; r < 32; r += 8)
        tile[ty + r][tx] = in[(size_t)(k0 + ty + r) * N + n0 + tx];
    __syncthreads();
    for (int r = 0; r < 32; r += 8)
        out[(size_t)(n0 + ty + r) * K + k0 + tx] = f2bfbits(tile[tx][ty + r]);
}

// ---------------------------------------------------------------------------
// GEMM: 128x128 tile, BK=64, global_load_lds staging, XOR-swizzled LDS.
// Epilogue: tanh-GELU (8 ops) + pair-packed dword stores via shfl_xor(1).
template <int GELU>
__global__ __launch_bounds__(256) void gemm_bt_kernel(
    const u16* __restrict__ A, const u16* __restrict__ Bt,
    const float* __restrict__ bias, u16* __restrict__ Cmat,
    int Nsz, int Ksz)
{
    __shared__ u16 As[128 * 64];
    __shared__ u16 Bs[128 * 64];
    const int tid  = threadIdx.x;
    const int wave = tid >> 6, lane = tid & 63;
    const int quad = lane >> 4, l16 = lane & 15;
    const int wm = (wave >> 1) * 64, wn = (wave & 1) * 64;
    const int m0 = blockIdx.y * 128, n0 = blockIdx.x * 128;

    const int srow = lane >> 3;
    const int scol = ((lane & 7) ^ srow) * 8;
    const u16* ap = A  + (size_t)(m0 + wave * 32 + srow) * Ksz + scol;
    const u16* bp = Bt + (size_t)(n0 + wave * 32 + srow) * Ksz + scol;
    const size_t dstep = (size_t)8 * Ksz;

    floatx4 acc[4][4];
#pragma unroll
    for (int i = 0; i < 4; i++)
#pragma unroll
        for (int j = 0; j < 4; j++)
            acc[i][j] = (floatx4){0.f, 0.f, 0.f, 0.f};

    const int l7 = l16 & 7;

    for (int k0 = 0; k0 < Ksz; k0 += 64) {
        __syncthreads();
#pragma unroll
        for (int d = 0; d < 4; d++) {
            gld_lds16(ap + d * dstep, As + (wave * 4 + d) * 512);
            gld_lds16(bp + d * dstep, Bs + (wave * 4 + d) * 512);
        }
        ap += 64; bp += 64;
        __syncthreads();

#pragma unroll
        for (int t = 0; t < 2; t++) {
            const int po = ((t * 4 + quad) ^ l7) * 8;
            bf16x8 af[4], bfr[4];
#pragma unroll
            for (int i = 0; i < 4; i++)
                af[i] = *reinterpret_cast<const bf16x8*>(As + (wm + i * 16 + l16) * 64 + po);
#pragma unroll
            for (int j = 0; j < 4; j++)
                bfr[j] = *reinterpret_cast<const bf16x8*>(Bs + (wn + j * 16 + l16) * 64 + po);
#pragma unroll
            for (int i = 0; i < 4; i++)
#pragma unroll
                for (int j = 0; j < 4; j++)
                    acc[i][j] = __builtin_amdgcn_mfma_f32_16x16x32_bf16(af[i], bfr[j], acc[i][j], 0, 0, 0);
        }
    }

    // epilogue: C layout col=lane&15, row=quad*4+reg. Pair lanes (l16, l16^1):
    // even lane stores rows {0,1}, odd lane rows {2,3} of the colpair (dword stores).
    float bv[4];
#pragma unroll
    for (int j = 0; j < 4; j++) bv[j] = bias[n0 + wn + j * 16 + l16];
    const int odd = l16 & 1;
#pragma unroll
    for (int i = 0; i < 4; i++) {
        const int row0 = m0 + wm + i * 16 + quad * 4;
#pragma unroll
        for (int j = 0; j < 4; j++) {
            float v[4];
#pragma unroll
            for (int r = 0; r < 4; r++) {
                float t = acc[i][j][r] + bv[j];
                if (GELU) {
                    float u = t * (0.7978845608f + 0.0356774081f * t * t);
                    float e = EXP2F(u * (2.0f * LOG2E));
                    t = t - t * __builtin_amdgcn_rcpf(e + 1.0f);
                }
                v[r] = t;
            }
            float pv0 = __shfl_xor(v[0], 1), pv1 = __shfl_xor(v[1], 1);
            float pv2 = __shfl_xor(v[2], 1), pv3 = __shfl_xor(v[3], 1);
            float lo0 = odd ? pv2 : v[0];
            float hi0 = odd ? v[2] : pv0;
            float lo1 = odd ? pv3 : v[1];
            float hi1 = odd ? v[3] : pv1;
            unsigned int d0 = (unsigned int)f2bfbits(lo0) | ((unsigned int)f2bfbits(hi0) << 16);
            unsigned int d1 = (unsigned int)f2bfbits(lo1) | ((unsigned int)f2bfbits(hi1) << 16);
            const int row  = row0 + odd * 2;
            const int colp = n0 + wn + j * 16 + (l16 & ~1);
            *reinterpret_cast<unsigned int*>(Cmat + (size_t)row * Nsz + colp)       = d0;
            *reinterpret_cast<unsigned int*>(Cmat + (size_t)(row + 1) * Nsz + colp) = d1;
        }
    }
}

// ---------------------------------------------------------------------------
// Flash attention, causal, S^T form. 512 threads = 8 waves x 16 q-rows
// (128 q-rows/block), k-tile 64, double-buffered K/V LDS, 1 barrier/iter.
// Block bx processes q-tiles {bx, 15-bx} (uniform 34 iters).
__global__ __launch_bounds__(512) void attn_kernel(const u16* __restrict__ qkv,
                                                   u16* __restrict__ y)
{
    __shared__ u16 Ks[2 * 64 * 64];   // [buf][key][d], chunk-swizzled pc = c ^ (key&7)
    __shared__ u16 Vt[2 * 64 * 64];   // [buf][d][key], dword-swizzled
    __shared__ u16 Pw[8][16 * 64];    // per-wave [q][key], chunk-swizzled pc = c ^ (q&7)
    const int tid  = threadIdx.x;
    const int wave = tid >> 6, lane = tid & 63;
    const int quad = lane >> 4, l16 = lane & 15;
    const int l7   = l16 & 7;
    const int h = blockIdx.y, b = blockIdx.z;
    const int rowbase = b * TT;
    const int S3C = 3 * TC;

    // staging roles: threads 0..255 -> K tile; 256..511 -> V tile
    const int srow = (tid >> 3) & 31;
    const int c8   = (tid & 7) * 8;
    const int pcK  = ((tid & 7) ^ (srow & 7)) * 8;    // K physical chunk
    const int pvb  = (srow + ((tid & 7) << 2)) & 31;  // V physical dword base
    const bool kRole = (tid < 256);
    // compute-side
    const int pcr = (quad ^ l7) * 8;
    unsigned int* const vtw = (unsigned int*)Vt;

    for (int pass = 0; pass < 2; pass++) {
        const int qt   = pass ? (15 - (int)blockIdx.x) : (int)blockIdx.x;
        const int q0b  = qt * 128;
        const int q0w  = q0b + wave * 16;
        const int kend = q0b + 128;

        __syncthreads();   // previous pass's LDS reads complete

        // Q as B-operand frags, pre-scaled by 0.125*log2(e)
        bf16x8 qf0, qf1;
        {
            const u16* qrow = qkv + (size_t)(rowbase + q0w + l16) * S3C + h * HD + quad * 8;
            bf16x8 t0 = *reinterpret_cast<const bf16x8*>(qrow);
            bf16x8 t1 = *reinterpret_cast<const bf16x8*>(qrow + 32);
#pragma unroll
            for (int i = 0; i < 8; i++) {
                t0[i] = (bf16)((float)t0[i] * (0.125f * LOG2E));
                t1[i] = (bf16)((float)t1[i] * (0.125f * LOG2E));
            }
            qf0 = t0; qf1 = t1;
        }

        float m_s = -__builtin_inff(), l_s = 0.f;
        floatx4 o_acc[4];
#pragma unroll
        for (int n = 0; n < 4; n++) o_acc[n] = (floatx4){0.f, 0.f, 0.f, 0.f};

        // role-dependent global base (row k=0) and prefetch of tile 0
        const u16* gp = kRole
            ? qkv + (size_t)(rowbase + srow) * S3C + TC + h * HD + c8
            : qkv + (size_t)(rowbase + 2 * srow) * S3C + 2 * TC + h * HD + c8;
        const size_t g2 = kRole ? (size_t)32 * S3C : (size_t)S3C;
        ushort8 r0 = *reinterpret_cast<const ushort8*>(gp);
        ushort8 r1 = *reinterpret_cast<const ushort8*>(gp + g2);

        int buf = 0;
        for (int k0 = 0; k0 < kend; k0 += 64) {
            // write prefetched regs into LDS[buf]
            if (kRole) {
                u16* kb = Ks + buf * 4096;
                *reinterpret_cast<ushort8*>(kb + srow * 64 + pcK)        = r0;
                *reinterpret_cast<ushort8*>(kb + (srow + 32) * 64 + pcK) = r1;
            } else {
                unsigned int* vb = vtw + buf * 2048;
#pragma unroll
                for (int j = 0; j < 8; j++) {
                    unsigned int pk = (unsigned int)r0[j] | ((unsigned int)r1[j] << 16);
                    vb[(c8 + j) * 32 + (pvb ^ (j << 2))] = pk;
                }
            }
            __syncthreads();

            if (k0 + 64 < kend) {   // prefetch next tile
                const u16* gn = gp + (size_t)(k0 + 64) * S3C;
                r0 = *reinterpret_cast<const ushort8*>(gn);
                r1 = *reinterpret_cast<const ushort8*>(gn + g2);
            }

            if (k0 <= q0w + 15) {   // wave not fully masked (wave-uniform)
                const u16* ksb = Ks + buf * 4096;
                floatx4 st[4];
#pragma unroll
                for (int t = 0; t < 4; t++) {
                    const u16* krowp = ksb + (t * 16 + l16) * 64;
                    bf16x8 ka  = *reinterpret_cast<const bf16x8*>(krowp + pcr);
                    bf16x8 kb2 = *reinterpret_cast<const bf16x8*>(krowp + (pcr ^ 32));
                    floatx4 s = (floatx4){0.f, 0.f, 0.f, 0.f};
                    s = __builtin_amdgcn_mfma_f32_16x16x32_bf16(ka, qf0, s, 0, 0, 0);
                    s = __builtin_amdgcn_mfma_f32_16x16x32_bf16(kb2, qf1, s, 0, 0, 0);
                    st[t] = s;
                }
                float v[16];
                if (k0 + 63 > q0w) {   // diagonal region: causal mask (wave-uniform)
                    const int kq = k0 - q0w;
#pragma unroll
                    for (int t = 0; t < 4; t++)
#pragma unroll
                        for (int r = 0; r < 4; r++)
                            v[t * 4 + r] = (t * 16 + quad * 4 + r + kq > l16)
                                               ? -__builtin_inff() : st[t][r];
                } else {
#pragma unroll
                    for (int t = 0; t < 4; t++)
#pragma unroll
                        for (int r = 0; r < 4; r++)
                            v[t * 4 + r] = st[t][r];
                }
                float mx = v[0];
#pragma unroll
                for (int i = 1; i < 16; i++) mx = fmaxf(mx, v[i]);
                mx = fmaxf(mx, __shfl_xor(mx, 16));
                mx = fmaxf(mx, __shfl_xor(mx, 32));
                const float mnew  = fmaxf(m_s, mx);
                const float alpha = EXP2F(m_s - mnew);
                float rs = 0.f;
                u16* const pwb = Pw[wave] + l16 * 64;
#pragma unroll
                for (int t = 0; t < 4; t++) {
                    float p0 = EXP2F(v[t * 4 + 0] - mnew);
                    float p1 = EXP2F(v[t * 4 + 1] - mnew);
                    float p2 = EXP2F(v[t * 4 + 2] - mnew);
                    float p3 = EXP2F(v[t * 4 + 3] - mnew);
                    rs += (p0 + p1) + (p2 + p3);
                    ushort4v pk;
                    pk.x = f2bfbits(p0); pk.y = f2bfbits(p1);
                    pk.z = f2bfbits(p2); pk.w = f2bfbits(p3);
                    *reinterpret_cast<ushort4v*>(
                        pwb + ((2 * t + (quad >> 1)) ^ l7) * 8 + (quad & 1) * 4) = pk;
                }
                rs += __shfl_xor(rs, 16);
                rs += __shfl_xor(rs, 32);
                l_s = l_s * alpha + rs;
                m_s = mnew;
#pragma unroll
                for (int n = 0; n < 4; n++) o_acc[n] *= alpha;

                bf16x8 pf0 = *reinterpret_cast<const bf16x8*>(pwb + pcr);
                bf16x8 pf1 = *reinterpret_cast<const bf16x8*>(pwb + (pcr ^ 32));
                const unsigned int* vbb = vtw + buf * 2048;
#pragma unroll
                for (int n = 0; n < 4; n++) {
                    const int dr  = n * 16 + l16;
                    const int pd0 = ((4 * (quad + 2 * n + (l16 >> 3))) & 31) ^ (l7 << 2);
                    bf16x8 vf0 = *reinterpret_cast<const bf16x8*>(vbb + dr * 32 + pd0);
                    bf16x8 vf1 = *reinterpret_cast<const bf16x8*>(vbb + dr * 32 + (pd0 ^ 16));
                    o_acc[n] = __builtin_amdgcn_mfma_f32_16x16x32_bf16(vf0, pf0, o_acc[n], 0, 0, 0);
                    o_acc[n] = __builtin_amdgcn_mfma_f32_16x16x32_bf16(vf1, pf1, o_acc[n], 0, 0, 0);
                }
            }
            buf ^= 1;
        }

        // write O^T: col=l16=q, row=quad*4+r=d_local
        const float li = 1.0f / l_s;
        u16* yrow = y + (size_t)(rowbase + q0w + l16) * TC + h * HD;
#pragma unroll
        for (int n = 0; n < 4; n++) {
            ushort4v ov;
            ov.x = f2bfbits(o_acc[n][0] * li);
            ov.y = f2bfbits(o_acc[n][1] * li);
            ov.z = f2bfbits(o_acc[n][2] * li);
            ov.w = f2bfbits(o_acc[n][3] * li);
            *reinterpret_cast<ushort4v*>(yrow + n * 16 + quad * 4) = ov;
        }
    }
}

// ---------------------------------------------------------------------------
template <typename AT, typename OT>
__global__ __launch_bounds__(256) void ln_kernel(
    const AT* __restrict__ a, const bf16* __restrict__ bres,
    const float* __restrict__ g, const float* __restrict__ be,
    OT* __restrict__ out)
{
    const int row = blockIdx.x;
    const int tid = threadIdx.x;
    const size_t base = (size_t)row * TC;
    float v[4];
    for (int i = 0; i < 4; i++) {
        const int c = tid + i * 256;
        v[i] = (float)a[base + c] + (float)bres[base + c];
    }
    float s  = v[0] + v[1] + v[2] + v[3];
    float sq = v[0]*v[0] + v[1]*v[1] + v[2]*v[2] + v[3]*v[3];
    for (int off = 32; off >= 1; off >>= 1) {
        s  += __shfl_xor(s, off, 64);
        sq += __shfl_xor(sq, off, 64);
    }
    __shared__ float red[8];
    const int wv = tid >> 6, lane = tid & 63;
    if (lane == 0) { red[wv] = s; red[4 + wv] = sq; }
    __syncthreads();
    s  = red[0] + red[1] + red[2] + red[3];
    sq = red[4] + red[5] + red[6] + red[7];
    const float mu   = s * (1.0f / TC);
    const float var  = sq * (1.0f / TC) - mu * mu;
    const float rsig = rsqrtf(var + 1e-5f);
    for (int i = 0; i < 4; i++) {
        const int c = tid + i * 256;
        out[base + c] = (OT)((v[i] - mu) * rsig * g[c] + be[c]);
    }
}

// ---------------------------------------------------------------------------
extern "C" void kernel_launch(void* const* d_in, const int* in_sizes, int n_in,
                              void* d_out, int out_size, void* d_ws, size_t ws_size,
                              hipStream_t stream)
{
    const float* x     = (const float*)d_in[0];
    const float* w_qkv = (const float*)d_in[1];
    const float* b_qkv = (const float*)d_in[2];
    const float* ln1_g = (const float*)d_in[3];
    const float* ln1_b = (const float*)d_in[4];
    const float* w_fc1 = (const float*)d_in[5];
    const float* b_fc1 = (const float*)d_in[6];
    const float* w_fc2 = (const float*)d_in[7];
    const float* b_fc2 = (const float*)d_in[8];
    const float* ln2_g = (const float*)d_in[9];
    const float* ln2_b = (const float*)d_in[10];
    float* out = (float*)d_out;

    char* ws = (char*)d_ws;
    const size_t MB = 1ull << 20;
    u16* xb    = (u16*)(ws + 0);        // [8192][1024]  16 MB
    u16* wqkvT = (u16*)(ws + 16 * MB);  // [3072][1024]   6 MB
    u16* wfc1T = (u16*)(ws + 22 * MB);  // [4096][1024]   8 MB
    u16* wfc2T = (u16*)(ws + 30 * MB);  // [1024][4096]   8 MB
    u16* qkv   = (u16*)(ws + 38 * MB);  // [8192][3072]  48 MB
    u16* yb    = (u16*)(ws + 86 * MB);  // [8192][1024]  16 MB
    u16* x1    = (u16*)(ws + 102 * MB); // [8192][1024]  16 MB
    u16* hb    = (u16*)(ws + 118 * MB); // [8192][4096]  64 MB
    u16* mlp   = (u16*)(ws + 38 * MB);  // reuse qkv region

    prep_kernel<<<19456, 256, 0, stream>>>(x, xb, w_qkv, wqkvT, w_fc1, wfc1T, w_fc2, wfc2T);

    gemm_bt_kernel<0><<<dim3(3 * TC / 128, MROWS / 128), 256, 0, stream>>>(
        xb, wqkvT, b_qkv, qkv, 3 * TC, TC);
    attn_kernel<<<dim3(8, NH, TB), 512, 0, stream>>>(qkv, yb);
    ln_kernel<float, bf16><<<MROWS, 256, 0, stream>>>(x, (const bf16*)yb, ln1_g, ln1_b, (bf16*)x1);
    gemm_bt_kernel<1><<<dim3(4 * TC / 128, MROWS / 128), 256, 0, stream>>>(
        (const u16*)x1, wfc1T, b_fc1, hb, 4 * TC, TC);
    gemm_bt_kernel<0><<<dim3(TC / 128, MROWS / 128), 256, 0, stream>>>(
        hb, wfc2T, b_fc2, mlp, TC, 4 * TC);
    ln_kernel<bf16, float><<<MROWS, 256, 0, stream>>>(
        (const bf16*)x1, (const bf16*)mlp, ln2_g, ln2_b, out);
}

// Round 6
// 455.096 us; speedup vs baseline: 1.8399x; 1.0226x over previous
//
#include <hip/hip_runtime.h>
#include <cstdint>
#include <cstddef>

// Problem constants
#define TB 4
#define TT 2048
#define TC 1024
#define NH 16
#define HD 64
#define MROWS (TB * TT)   // 8192

typedef __bf16 bf16;
typedef unsigned short u16;
typedef __bf16 bf16x8 __attribute__((ext_vector_type(8)));
typedef float floatx4 __attribute__((ext_vector_type(4)));
typedef unsigned short ushort8 __attribute__((ext_vector_type(8)));
typedef unsigned short ushort4v __attribute__((ext_vector_type(4)));

#define LOG2E 1.4426950408889634f

static __device__ __forceinline__ u16 f2bfbits(float f) {
    bf16 b = (bf16)f;
    return __builtin_bit_cast(u16, b);
}

#if __has_builtin(__builtin_amdgcn_exp2f)
#define EXP2F(x) __builtin_amdgcn_exp2f(x)
#else
#define EXP2F(x) exp2f(x)
#endif

// async global->LDS 16B (dest = wave-uniform base + lane*16)
static __device__ __forceinline__ void gld_lds16(const u16* g, const u16* lds) {
    __builtin_amdgcn_global_load_lds(
        (const __attribute__((address_space(1))) unsigned int*)(uintptr_t)g,
        (__attribute__((address_space(3))) unsigned int*)(unsigned int)(uintptr_t)lds,
        16, 0, 0);
}

// ---------------------------------------------------------------------------
// Unified prep: x cast (blocks 0..8191) + three weight transposes.
__global__ __launch_bounds__(256) void prep_kernel(
    const float* __restrict__ x, u16* __restrict__ xb,
    const float* __restrict__ w_qkv, u16* __restrict__ wqkvT,
    const float* __restrict__ w_fc1, u16* __restrict__ wfc1T,
    const float* __restrict__ w_fc2, u16* __restrict__ wfc2T)
{
    const int tid = threadIdx.x;
    int blk = blockIdx.x;
    if (blk < 8192) {   // cast: whole block uniform path
        const int i = blk * 256 + tid;
        float4 v = reinterpret_cast<const float4*>(x)[i];
        ushort4v o;
        o.x = f2bfbits(v.x); o.y = f2bfbits(v.y); o.z = f2bfbits(v.z); o.w = f2bfbits(v.w);
        reinterpret_cast<ushort4v*>(xb)[i] = o;
        return;
    }
    blk -= 8192;
    const float* in; u16* out; int K, N, bx, by;
    if (blk < 3072)      { in = w_qkv; out = wqkvT; K = TC;     N = 3 * TC; bx = blk % 96;  by = blk / 96; }
    else if (blk < 7168) { blk -= 3072; in = w_fc1; out = wfc1T; K = TC;    N = 4 * TC; bx = blk & 127; by = blk >> 7; }
    else                 { blk -= 7168; in = w_fc2; out = wfc2T; K = 4 * TC; N = TC;    bx = blk & 31;  by = blk >> 5; }
    __shared__ float tile[32][33];
    const int n0 = bx * 32, k0 = by * 32;
    const int tx = tid & 31, ty = tid >> 5;   // 32 x 8
    for (int r = 0; r < 32; r += 8)
        tile[ty + r][tx] = in[(size_t)(k0 + ty + r) * N + n0 + tx];
    __syncthreads();
    for (int r = 0; r < 32; r += 8)
        out[(size_t)(n0 + ty + r) * K + k0 + tx] = f2bfbits(tile[tx][ty + r]);
}

// ---------------------------------------------------------------------------
// GEMM: 128x256 block tile, BK=64, 4 waves each 64x128 (4x8 mfma tiles).
// global_load_lds staging, XOR chunk-swizzled LDS (conflict-free b128 reads).
// m-grouped XCD swizzle: bid&7 = XCD slot; blocks sharing an A-strip are
// co-resident on one XCD (A fetched ~once). Grid must be Nb*64 blocks.
template <int GELU>
__global__ __launch_bounds__(256, 2) void gemm_bt_kernel(
    const u16* __restrict__ A, const u16* __restrict__ Bt,
    const float* __restrict__ bias, u16* __restrict__ Cmat,
    int Nb, int Ksz)
{
    __shared__ u16 As[128 * 64];
    __shared__ u16 Bs[256 * 64];
    const int tid  = threadIdx.x;
    const int wave = tid >> 6, lane = tid & 63;
    const int quad = lane >> 4, l16 = lane & 15;
    const int Nsz = Nb * 256;
    const int bid = blockIdx.x;
    const int xcd = bid & 7, qb = bid >> 3;
    const int m0 = (xcd * 8 + qb / Nb) * 128;
    const int n0 = (qb % Nb) * 256;
    const int wm = (wave >> 1) * 64, wn = (wave & 1) * 128;

    const int srow = lane >> 3;
    const int scol = ((lane & 7) ^ srow) * 8;
    const u16* ap = A  + (size_t)(m0 + wave * 32 + srow) * Ksz + scol;
    const u16* bp = Bt + (size_t)(n0 + wave * 8  + srow) * Ksz + scol;
    const size_t astep = (size_t)8  * Ksz;
    const size_t bstep = (size_t)32 * Ksz;

    floatx4 acc[4][8];
#pragma unroll
    for (int i = 0; i < 4; i++)
#pragma unroll
        for (int j = 0; j < 8; j++)
            acc[i][j] = (floatx4){0.f, 0.f, 0.f, 0.f};

    const int l7 = l16 & 7;

    for (int k0 = 0; k0 < Ksz; k0 += 64) {
        __syncthreads();
#pragma unroll
        for (int d = 0; d < 4; d++)
            gld_lds16(ap + d * astep, As + (wave * 4 + d) * 512);
#pragma unroll
        for (int d = 0; d < 8; d++)
            gld_lds16(bp + d * bstep, Bs + d * 2048 + wave * 512);
        ap += 64; bp += 64;
        __syncthreads();

#pragma unroll
        for (int t = 0; t < 2; t++) {
            const int po = ((t * 4 + quad) ^ l7) * 8;
            bf16x8 af[4], bfr[8];
#pragma unroll
            for (int i = 0; i < 4; i++)
                af[i] = *reinterpret_cast<const bf16x8*>(As + (wm + i * 16 + l16) * 64 + po);
#pragma unroll
            for (int j = 0; j < 8; j++)
                bfr[j] = *reinterpret_cast<const bf16x8*>(Bs + (wn + j * 16 + l16) * 64 + po);
#pragma unroll
            for (int i = 0; i < 4; i++)
#pragma unroll
                for (int j = 0; j < 8; j++)
                    acc[i][j] = __builtin_amdgcn_mfma_f32_16x16x32_bf16(af[i], bfr[j], acc[i][j], 0, 0, 0);
        }
    }

    // epilogue: C layout col=lane&15, row=quad*4+reg. Pair lanes (l16, l16^1):
    // even lane stores rows {0,1}, odd lane rows {2,3} of the colpair (dword stores).
    float bv[8];
#pragma unroll
    for (int j = 0; j < 8; j++) bv[j] = bias[n0 + wn + j * 16 + l16];
    const int odd = l16 & 1;
#pragma unroll
    for (int i = 0; i < 4; i++) {
        const int row0 = m0 + wm + i * 16 + quad * 4;
#pragma unroll
        for (int j = 0; j < 8; j++) {
            float v[4];
#pragma unroll
            for (int r = 0; r < 4; r++) {
                float t = acc[i][j][r] + bv[j];
                if (GELU) {
                    float u = t * (0.7978845608f + 0.0356774081f * t * t);
                    float e = EXP2F(u * (2.0f * LOG2E));
                    t = t - t * __builtin_amdgcn_rcpf(e + 1.0f);
                }
                v[r] = t;
            }
            float pv0 = __shfl_xor(v[0], 1), pv1 = __shfl_xor(v[1], 1);
            float pv2 = __shfl_xor(v[2], 1), pv3 = __shfl_xor(v[3], 1);
            float lo0 = odd ? pv2 : v[0];
            float hi0 = odd ? v[2] : pv0;
            float lo1 = odd ? pv3 : v[1];
            float hi1 = odd ? v[3] : pv1;
            unsigned int d0 = (unsigned int)f2bfbits(lo0) | ((unsigned int)f2bfbits(hi0) << 16);
            unsigned int d1 = (unsigned int)f2bfbits(lo1) | ((unsigned int)f2bfbits(hi1) << 16);
            const int row  = row0 + odd * 2;
            const int colp = n0 + wn + j * 16 + (l16 & ~1);
            *reinterpret_cast<unsigned int*>(Cmat + (size_t)row * Nsz + colp)       = d0;
            *reinterpret_cast<unsigned int*>(Cmat + (size_t)(row + 1) * Nsz + colp) = d1;
        }
    }
}

// ---------------------------------------------------------------------------
// Flash attention, causal, S^T form. 512 threads = 8 waves x 16 q-rows
// (128 q-rows/block), k-tile 64, double-buffered K/V LDS, 1 barrier/iter.
// Block bx processes q-tiles {bx, 15-bx} (uniform 34 iters).
__global__ __launch_bounds__(512) void attn_kernel(const u16* __restrict__ qkv,
                                                   u16* __restrict__ y)
{
    __shared__ u16 Ks[2 * 64 * 64];   // [buf][key][d], chunk-swizzled pc = c ^ (key&7)
    __shared__ u16 Vt[2 * 64 * 64];   // [buf][d][key], dword-swizzled
    __shared__ u16 Pw[8][16 * 64];    // per-wave [q][key], chunk-swizzled pc = c ^ (q&7)
    const int tid  = threadIdx.x;
    const int wave = tid >> 6, lane = tid & 63;
    const int quad = lane >> 4, l16 = lane & 15;
    const int l7   = l16 & 7;
    const int h = blockIdx.y, b = blockIdx.z;
    const int rowbase = b * TT;
    const int S3C = 3 * TC;

    // staging roles: threads 0..255 -> K tile; 256..511 -> V tile
    const int srow = (tid >> 3) & 31;
    const int c8   = (tid & 7) * 8;
    const int pcK  = ((tid & 7) ^ (srow & 7)) * 8;    // K physical chunk
    const int pvb  = (srow + ((tid & 7) << 2)) & 31;  // V physical dword base
    const bool kRole = (tid < 256);
    // compute-side
    const int pcr = (quad ^ l7) * 8;
    unsigned int* const vtw = (unsigned int*)Vt;

    for (int pass = 0; pass < 2; pass++) {
        const int qt   = pass ? (15 - (int)blockIdx.x) : (int)blockIdx.x;
        const int q0b  = qt * 128;
        const int q0w  = q0b + wave * 16;
        const int kend = q0b + 128;

        __syncthreads();   // previous pass's LDS reads complete

        // Q as B-operand frags, pre-scaled by 0.125*log2(e)
        bf16x8 qf0, qf1;
        {
            const u16* qrow = qkv + (size_t)(rowbase + q0w + l16) * S3C + h * HD + quad * 8;
            bf16x8 t0 = *reinterpret_cast<const bf16x8*>(qrow);
            bf16x8 t1 = *reinterpret_cast<const bf16x8*>(qrow + 32);
#pragma unroll
            for (int i = 0; i < 8; i++) {
                t0[i] = (bf16)((float)t0[i] * (0.125f * LOG2E));
                t1[i] = (bf16)((float)t1[i] * (0.125f * LOG2E));
            }
            qf0 = t0; qf1 = t1;
        }

        float m_s = -__builtin_inff(), l_s = 0.f;
        floatx4 o_acc[4];
#pragma unroll
        for (int n = 0; n < 4; n++) o_acc[n] = (floatx4){0.f, 0.f, 0.f, 0.f};

        // role-dependent global base (row k=0) and prefetch of tile 0
        const u16* gp = kRole
            ? qkv + (size_t)(rowbase + srow) * S3C + TC + h * HD + c8
            : qkv + (size_t)(rowbase + 2 * srow) * S3C + 2 * TC + h * HD + c8;
        const size_t g2 = kRole ? (size_t)32 * S3C : (size_t)S3C;
        ushort8 r0 = *reinterpret_cast<const ushort8*>(gp);
        ushort8 r1 = *reinterpret_cast<const ushort8*>(gp + g2);

        int buf = 0;
        for (int k0 = 0; k0 < kend; k0 += 64) {
            // write prefetched regs into LDS[buf]
            if (kRole) {
                u16* kb = Ks + buf * 4096;
                *reinterpret_cast<ushort8*>(kb + srow * 64 + pcK)        = r0;
                *reinterpret_cast<ushort8*>(kb + (srow + 32) * 64 + pcK) = r1;
            } else {
                unsigned int* vb = vtw + buf * 2048;
#pragma unroll
                for (int j = 0; j < 8; j++) {
                    unsigned int pk = (unsigned int)r0[j] | ((unsigned int)r1[j] << 16);
                    vb[(c8 + j) * 32 + (pvb ^ (j << 2))] = pk;
                }
            }
            __syncthreads();

            if (k0 + 64 < kend) {   // prefetch next tile
                const u16* gn = gp + (size_t)(k0 + 64) * S3C;
                r0 = *reinterpret_cast<const ushort8*>(gn);
                r1 = *reinterpret_cast<const ushort8*>(gn + g2);
            }

            if (k0 <= q0w + 15) {   // wave not fully masked (wave-uniform)
                const u16* ksb = Ks + buf * 4096;
                floatx4 st[4];
#pragma unroll
                for (int t = 0; t < 4; t++) {
                    const u16* krowp = ksb + (t * 16 + l16) * 64;
                    bf16x8 ka  = *reinterpret_cast<const bf16x8*>(krowp + pcr);
                    bf16x8 kb2 = *reinterpret_cast<const bf16x8*>(krowp + (pcr ^ 32));
                    floatx4 s = (floatx4){0.f, 0.f, 0.f, 0.f};
                    s = __builtin_amdgcn_mfma_f32_16x16x32_bf16(ka, qf0, s, 0, 0, 0);
                    s = __builtin_amdgcn_mfma_f32_16x16x32_bf16(kb2, qf1, s, 0, 0, 0);
                    st[t] = s;
                }
                float v[16];
                if (k0 + 63 > q0w) {   // diagonal region: causal mask (wave-uniform)
                    const int kq = k0 - q0w;
#pragma unroll
                    for (int t = 0; t < 4; t++)
#pragma unroll
                        for (int r = 0; r < 4; r++)
                            v[t * 4 + r] = (t * 16 + quad * 4 + r + kq > l16)
                                               ? -__builtin_inff() : st[t][r];
                } else {
#pragma unroll
                    for (int t = 0; t < 4; t++)
#pragma unroll
                        for (int r = 0; r < 4; r++)
                            v[t * 4 + r] = st[t][r];
                }
                float mx = v[0];
#pragma unroll
                for (int i = 1; i < 16; i++) mx = fmaxf(mx, v[i]);
                mx = fmaxf(mx, __shfl_xor(mx, 16));
                mx = fmaxf(mx, __shfl_xor(mx, 32));
                const float mnew  = fmaxf(m_s, mx);
                const float alpha = EXP2F(m_s - mnew);
                float rs = 0.f;
                u16* const pwb = Pw[wave] + l16 * 64;
#pragma unroll
                for (int t = 0; t < 4; t++) {
                    float p0 = EXP2F(v[t * 4 + 0] - mnew);
                    float p1 = EXP2F(v[t * 4 + 1] - mnew);
                    float p2 = EXP2F(v[t * 4 + 2] - mnew);
                    float p3 = EXP2F(v[t * 4 + 3] - mnew);
                    rs += (p0 + p1) + (p2 + p3);
                    ushort4v pk;
                    pk.x = f2bfbits(p0); pk.y = f2bfbits(p1);
                    pk.z = f2bfbits(p2); pk.w = f2bfbits(p3);
                    *reinterpret_cast<ushort4v*>(
                        pwb + ((2 * t + (quad >> 1)) ^ l7) * 8 + (quad & 1) * 4) = pk;
                }
                rs += __shfl_xor(rs, 16);
                rs += __shfl_xor(rs, 32);
                l_s = l_s * alpha + rs;
                m_s = mnew;
#pragma unroll
                for (int n = 0; n < 4; n++) o_acc[n] *= alpha;

                bf16x8 pf0 = *reinterpret_cast<const bf16x8*>(pwb + pcr);
                bf16x8 pf1 = *reinterpret_cast<const bf16x8*>(pwb + (pcr ^ 32));
                const unsigned int* vbb = vtw + buf * 2048;
#pragma unroll
                for (int n = 0; n < 4; n++) {
                    const int dr  = n * 16 + l16;
                    const int pd0 = ((4 * (quad + 2 * n + (l16 >> 3))) & 31) ^ (l7 << 2);
                    bf16x8 vf0 = *reinterpret_cast<const bf16x8*>(vbb + dr * 32 + pd0);
                    bf16x8 vf1 = *reinterpret_cast<const bf16x8*>(vbb + dr * 32 + (pd0 ^ 16));
                    o_acc[n] = __builtin_amdgcn_mfma_f32_16x16x32_bf16(vf0, pf0, o_acc[n], 0, 0, 0);
                    o_acc[n] = __builtin_amdgcn_mfma_f32_16x16x32_bf16(vf1, pf1, o_acc[n], 0, 0, 0);
                }
            }
            buf ^= 1;
        }

        // write O^T: col=l16=q, row=quad*4+r=d_local
        const float li = 1.0f / l_s;
        u16* yrow = y + (size_t)(rowbase + q0w + l16) * TC + h * HD;
#pragma unroll
        for (int n = 0; n < 4; n++) {
            ushort4v ov;
            ov.x = f2bfbits(o_acc[n][0] * li);
            ov.y = f2bfbits(o_acc[n][1] * li);
            ov.z = f2bfbits(o_acc[n][2] * li);
            ov.w = f2bfbits(o_acc[n][3] * li);
            *reinterpret_cast<ushort4v*>(yrow + n * 16 + quad * 4) = ov;
        }
    }
}

// ---------------------------------------------------------------------------
template <typename AT, typename OT>
__global__ __launch_bounds__(256) void ln_kernel(
    const AT* __restrict__ a, const bf16* __restrict__ bres,
    const float* __restrict__ g, const float* __restrict__ be,
    OT* __restrict__ out)
{
    const int row = blockIdx.x;
    const int tid = threadIdx.x;
    const size_t base = (size_t)row * TC;
    float v[4];
    for (int i = 0; i < 4; i++) {
        const int c = tid + i * 256;
        v[i] = (float)a[base + c] + (float)bres[base + c];
    }
    float s  = v[0] + v[1] + v[2] + v[3];
    float sq = v[0]*v[0] + v[1]*v[1] + v[2]*v[2] + v[3]*v[3];
    for (int off = 32; off >= 1; off >>= 1) {
        s  += __shfl_xor(s, off, 64);
        sq += __shfl_xor(sq, off, 64);
    }
    __shared__ float red[8];
    const int wv = tid >> 6, lane = tid & 63;
    if (lane == 0) { red[wv] = s; red[4 + wv] = sq; }
    __syncthreads();
    s  = red[0] + red[1] + red[2] + red[3];
    sq = red[4] + red[5] + red[6] + red[7];
    const float mu   = s * (1.0f / TC);
    const float var  = sq * (1.0f / TC) - mu * mu;
    const float rsig = rsqrtf(var + 1e-5f);
    for (int i = 0; i < 4; i++) {
        const int c = tid + i * 256;
        out[base + c] = (OT)((v[i] - mu) * rsig * g[c] + be[c]);
    }
}

// ---------------------------------------------------------------------------
extern "C" void kernel_launch(void* const* d_in, const int* in_sizes, int n_in,
                              void* d_out, int out_size, void* d_ws, size_t ws_size,
                              hipStream_t stream)
{
    const float* x     = (const float*)d_in[0];
    const float* w_qkv = (const float*)d_in[1];
    const float* b_qkv = (const float*)d_in[2];
    const float* ln1_g = (const float*)d_in[3];
    const float* ln1_b = (const float*)d_in[4];
    const float* w_fc1 = (const float*)d_in[5];
    const float* b_fc1 = (const float*)d_in[6];
    const float* w_fc2 = (const float*)d_in[7];
    const float* b_fc2 = (const float*)d_in[8];
    const float* ln2_g = (const float*)d_in[9];
    const float* ln2_b = (const float*)d_in[10];
    float* out = (float*)d_out;

    char* ws = (char*)d_ws;
    const size_t MB = 1ull << 20;
    u16* xb    = (u16*)(ws + 0);        // [8192][1024]  16 MB
    u16* wqkvT = (u16*)(ws + 16 * MB);  // [3072][1024]   6 MB
    u16* wfc1T = (u16*)(ws + 22 * MB);  // [4096][1024]   8 MB
    u16* wfc2T = (u16*)(ws + 30 * MB);  // [1024][4096]   8 MB
    u16* qkv   = (u16*)(ws + 38 * MB);  // [8192][3072]  48 MB
    u16* yb    = (u16*)(ws + 86 * MB);  // [8192][1024]  16 MB
    u16* x1    = (u16*)(ws + 102 * MB); // [8192][1024]  16 MB
    u16* hb    = (u16*)(ws + 118 * MB); // [8192][4096]  64 MB
    u16* mlp   = (u16*)(ws + 38 * MB);  // reuse qkv region

    prep_kernel<<<19456, 256, 0, stream>>>(x, xb, w_qkv, wqkvT, w_fc1, wfc1T, w_fc2, wfc2T);

    gemm_bt_kernel<0><<<12 * 64, 256, 0, stream>>>(xb, wqkvT, b_qkv, qkv, 12, TC);
    attn_kernel<<<dim3(8, NH, TB), 512, 0, stream>>>(qkv, yb);
    ln_kernel<float, bf16><<<MROWS, 256, 0, stream>>>(x, (const bf16*)yb, ln1_g, ln1_b, (bf16*)x1);
    gemm_bt_kernel<1><<<16 * 64, 256, 0, stream>>>((const u16*)x1, wfc1T, b_fc1, hb, 16, TC);
    gemm_bt_kernel<0><<<4 * 64, 256, 0, stream>>>(hb, wfc2T, b_fc2, mlp, 4, 4 * TC);
    ln_kernel<bf16, float><<<MROWS, 256, 0, stream>>>(
        (const bf16*)x1, (const bf16*)mlp, ln2_g, ln2_b, out);
}